// Round 6
// baseline (623.006 us; speedup 1.0000x reference)
//
#include <hip/hip_runtime.h>
#include <math.h>

#define NN 50000
#define EE 800000
#define D 128
#define EDIM 32
#define LL 3
#define NT 2
#define ET 3
#define NB 196       // ceil(NN/256)
#define NPAD 50080   // >= align64(c0) + c1 for any split; multiple of 32
#define NT16 3130    // NPAD/16 (16-row wave tiles)
#define NBLK16 783   // ceil(NT16/4), 4 waves/block

typedef _Float16 f16x8 __attribute__((ext_vector_type(8)));
typedef float f32x4 __attribute__((ext_vector_type(4)));

// split 8 consecutive fp32 into hi/lo f16 halves (hi + lo == x to ~2^-21 rel)
__device__ __forceinline__ void cvt8(const float4 u, const float4 v, f16x8& hi, f16x8& lo) {
    float x[8] = {u.x, u.y, u.z, u.w, v.x, v.y, v.z, v.w};
#pragma unroll
    for (int e = 0; e < 8; e++) {
        _Float16 h = (_Float16)x[e];
        hi[e] = h;
        lo[e] = (_Float16)(x[e] - (float)h);
    }
}

// ---------------- node-type permutation (deterministic, scan-based) ----------------
// packed counts: low 16 = type0, high 16 = type1 (totals <= 50000 < 65536)
__global__ __launch_bounds__(256) void k_pcount(const int* __restrict__ nt, int* __restrict__ pc) {
    __shared__ int s[256];
    int d = blockIdx.x * 256 + threadIdx.x;
    int ind = 0;
    if (d < NN) ind = (nt[d] == 0) ? 1 : 0x10000;
    s[threadIdx.x] = ind;
    __syncthreads();
    for (int st = 128; st; st >>= 1) {
        if (threadIdx.x < st) s[threadIdx.x] += s[threadIdx.x + st];
        __syncthreads();
    }
    if (threadIdx.x == 0) pc[blockIdx.x] = s[0];
}

__global__ __launch_bounds__(256) void k_pscan(const int* __restrict__ pc, int* __restrict__ po,
                                               int* __restrict__ meta) {
    __shared__ int s[256];
    int t = threadIdx.x;
    int v = (t < NB) ? pc[t] : 0;
    s[t] = v;
    __syncthreads();
    for (int st = 1; st < 256; st <<= 1) {
        int add = (t >= st) ? s[t - st] : 0;
        __syncthreads();
        s[t] += add;
        __syncthreads();
    }
    if (t < NB) po[t] = s[t] - v;                     // exclusive packed block offsets
    if (t == 0) {
        int tot = s[255];
        meta[3] = ((tot & 0xffff) + 63) & ~63;        // aligned base for type-1 region
    }
}

__global__ __launch_bounds__(256) void k_passign(const int* __restrict__ nt, const int* __restrict__ po,
                                                 const int* __restrict__ meta,
                                                 int* __restrict__ pos, int* __restrict__ inv) {
    __shared__ int s[256];
    int t = threadIdx.x;
    int d = blockIdx.x * 256 + t;
    int ty = (d < NN) ? nt[d] : -1;
    int ind = (ty == 0) ? 1 : ((ty == 1) ? 0x10000 : 0);
    s[t] = ind;
    __syncthreads();
    for (int st = 1; st < 256; st <<= 1) {
        int add = (t >= st) ? s[t - st] : 0;
        __syncthreads();
        s[t] += add;
        __syncthreads();
    }
    if (d >= NN) return;
    int excl = s[t] - ind;
    int pop = po[blockIdx.x];
    int p;
    if (ty == 0) p = (pop & 0xffff) + (excl & 0xffff);
    else         p = meta[3] + (pop >> 16) + (excl >> 16);
    pos[d] = p;
    inv[p] = d;
}

__global__ __launch_bounds__(256) void k_permx(const float* __restrict__ x, const int* __restrict__ pos,
                                               float* __restrict__ h0) {
    int flat = blockIdx.x * 256 + threadIdx.x;
    if (flat >= NN * 32) return;
    int d = flat >> 5, f4 = flat & 31;
    int p = pos[d];
    ((float4*)h0)[(size_t)p * 32 + f4] = ((const float4*)x)[(size_t)d * 32 + f4];
}

// ---------------- histogram of dst ----------------
__global__ __launch_bounds__(256) void k_hist(const int* __restrict__ dst, int* __restrict__ deg) {
    int e = blockIdx.x * 256 + threadIdx.x;
    if (e < EE) atomicAdd(&deg[dst[e]], 1);
}

// ---------------- 2-level exclusive scan ----------------
__global__ __launch_bounds__(256) void k_scan_bsum(const int* __restrict__ deg, int* __restrict__ bsum) {
    __shared__ int s[256];
    int t = threadIdx.x;
    int d = blockIdx.x * 256 + t;
    s[t] = (d < NN) ? deg[d] : 0;
    __syncthreads();
    for (int st = 128; st > 0; st >>= 1) {
        if (t < st) s[t] += s[t + st];
        __syncthreads();
    }
    if (t == 0) bsum[blockIdx.x] = s[0];
}

__global__ __launch_bounds__(256) void k_scan_boff(const int* __restrict__ bsum, int* __restrict__ boff) {
    __shared__ int s[256];
    int t = threadIdx.x;
    s[t] = (t < NB) ? bsum[t] : 0;
    __syncthreads();
    for (int st = 1; st < 256; st <<= 1) {
        int add = (t >= st) ? s[t - st] : 0;
        __syncthreads();
        s[t] += add;
        __syncthreads();
    }
    if (t < NB) boff[t] = (t == 0) ? 0 : s[t - 1];
}

__global__ __launch_bounds__(256) void k_scan_offs(const int* __restrict__ deg, const int* __restrict__ boff,
                                                   int* __restrict__ offs, int* __restrict__ cur) {
    __shared__ int s[256];
    int t = threadIdx.x;
    int d = blockIdx.x * 256 + t;
    int v = (d < NN) ? deg[d] : 0;
    s[t] = v;
    __syncthreads();
    for (int st = 1; st < 256; st <<= 1) {
        int add = (t >= st) ? s[t - st] : 0;
        __syncthreads();
        s[t] += add;
        __syncthreads();
    }
    if (d < NN) {
        int excl = s[t] - v + boff[blockIdx.x];
        offs[d] = excl;
        cur[d]  = excl;
    }
}

// ------------- per-edge scalars (all 3 layers) packed + scattered into dst-sorted order -------------
// LDS weight rows padded to stride 33 so the 3 edge-type rows (64 floats apart unpadded)
// land in distinct banks.
__global__ __launch_bounds__(256) void k_edge(const float* __restrict__ edge_attr,
                                              const float* __restrict__ edge_W,
                                              const float* __restrict__ edge_b,
                                              const float* __restrict__ emb,
                                              const int* __restrict__ ei,
                                              const int* __restrict__ etype,
                                              const int* __restrict__ pos,
                                              int* __restrict__ cur,
                                              float4* __restrict__ esort) {
    __shared__ float eWl[18 * 33];   // 18 rows x 32 floats, stride 33
    __shared__ float ebd[18];        // emb·eW + eb
    int t0 = threadIdx.x;
    for (int i = t0; i < 18 * EDIM; i += 256) eWl[(i >> 5) * 33 + (i & 31)] = edge_W[i];
    __syncthreads();
    if (t0 < 18) {
        int l = t0 / (ET * 2);
        int rem = t0 % (ET * 2);
        int tt = rem / 2;
        float sum = edge_b[t0];
        const float* em = emb + (l * ET + tt) * EDIM;
        const float* wq  = eWl + t0 * 33;
        for (int c = 0; c < EDIM; c++) sum += em[c] * wq[c];
        ebd[t0] = sum;
    }
    __syncthreads();
    int e = blockIdx.x * 256 + t0;
    if (e >= EE) return;

    float a[EDIM];
    const float4* ap = (const float4*)(edge_attr + (size_t)e * EDIM);
#pragma unroll
    for (int i = 0; i < EDIM / 4; i++) {
        float4 v = ap[i];
        a[4 * i + 0] = v.x; a[4 * i + 1] = v.y; a[4 * i + 2] = v.z; a[4 * i + 3] = v.w;
    }
    int tt = etype[e];
    float dir  = a[EDIM - 2];
    float pump = a[EDIM - 1];
    float sign = dir * 2.f - 1.f;
    float speed = pump * (dir > 0.f ? dir : 1.f);
    int src = ei[e];
    int dst = ei[EE + e];
    int sp = pos[src];
    int p = atomicAdd(&cur[dst], 1);
    float Av[LL], Bv[LL];
#pragma unroll
    for (int l = 0; l < LL; l++) {
        const float* w0 = eWl + ((l * ET + tt) * 2 + 0) * 33;
        const float* w1 = w0 + 33;
        float r0 = ebd[(l * ET + tt) * 2 + 0];
        float r1 = ebd[(l * ET + tt) * 2 + 1];
#pragma unroll
        for (int c = 0; c < EDIM; c++) { r0 += a[c] * w0[c]; r1 += a[c] * w1[c]; }
        float gain = fmaxf(r0, 0.f) + log1pf(expf(-fabsf(r0)));   // stable softplus
        float bias = 0.f;
        if (tt == 1) { gain *= speed; bias = r1 * speed; }        // PUMP == 1
        Av[l] = sign * gain;
        Bv[l] = sign * bias;
    }
    float4 e0 = make_float4(__int_as_float(sp), Av[0], Av[1], Av[2]);
    float4 e1 = make_float4(Bv[0], Bv[1], Bv[2], 0.f);
    esort[(size_t)p * 2 + 0] = e0;
    esort[(size_t)p * 2 + 1] = e1;
}

// ------------- gather: aggr[pos[d]] = sum A*h[spos] - sA*h[pos[d]] + sB -------------
// 2 nodes / block; per node 4 edge-workers x 32 float4-lanes; 2 edges in flight per worker.
__global__ __launch_bounds__(256) void k_gather(const float* __restrict__ h,
                                                const int* __restrict__ offs,
                                                const int* __restrict__ deg,
                                                const int* __restrict__ pos,
                                                const float4* __restrict__ esort,
                                                int layer,
                                                float* __restrict__ aggr) {
    __shared__ float4 rbuf[2][32];
    __shared__ float  rsum[2][2];
    int local = threadIdx.x;
    int nb = local >> 7;                    // node within block
    int node = blockIdx.x * 2 + nb;
    int t = local & 127;
    int w = t >> 5;                         // worker 0..3
    int f4 = t & 31;                        // feature-quad lane
    int start = offs[node];
    int n = deg[node];
    int p = pos[node];

    float4 acc = make_float4(0.f, 0.f, 0.f, 0.f);
    float sA = 0.f, sB = 0.f;
    for (int k = w; k < n; k += 8) {
        int k2 = k + 4;
        bool ok2 = (k2 < n);
        size_t i1 = (size_t)(start + k) * 2;
        size_t i2 = ok2 ? (size_t)(start + k2) * 2 : i1;
        float4 e0 = esort[i1];
        float4 e1 = esort[i1 + 1];
        float4 f0 = esort[i2];
        float4 f1 = esort[i2 + 1];
        int s1 = __float_as_int(e0.x);
        int s2 = __float_as_int(f0.x);
        float4 h1 = *(const float4*)&h[(size_t)s1 * D + 4 * f4];
        float4 h2 = *(const float4*)&h[(size_t)s2 * D + 4 * f4];
        float A1 = (layer == 0) ? e0.y : ((layer == 1) ? e0.z : e0.w);
        float B1 = (layer == 0) ? e1.x : ((layer == 1) ? e1.y : e1.z);
        float A2 = (layer == 0) ? f0.y : ((layer == 1) ? f0.z : f0.w);
        float B2 = (layer == 0) ? f1.x : ((layer == 1) ? f1.y : f1.z);
        if (!ok2) { A2 = 0.f; B2 = 0.f; }
        acc.x += A1 * h1.x + A2 * h2.x;
        acc.y += A1 * h1.y + A2 * h2.y;
        acc.z += A1 * h1.z + A2 * h2.z;
        acc.w += A1 * h1.w + A2 * h2.w;
        sA += A1 + A2; sB += B1 + B2;
    }
    // combine worker pairs within wave (lanes l and l^32)
    acc.x += __shfl_xor(acc.x, 32); acc.y += __shfl_xor(acc.y, 32);
    acc.z += __shfl_xor(acc.z, 32); acc.w += __shfl_xor(acc.w, 32);
    sA += __shfl_xor(sA, 32); sB += __shfl_xor(sB, 32);
    // cross-wave combine via LDS: upper wave of each node writes, lower reads
    if (((local >> 6) & 1) == 1 && (t & 63) < 32) {
        rbuf[nb][f4] = acc;
        if (f4 == 0) { rsum[nb][0] = sA; rsum[nb][1] = sB; }
    }
    __syncthreads();
    if (((local >> 6) & 1) == 0 && (t & 63) < 32) {
        float4 o = rbuf[nb][f4];
        float sAt = sA + rsum[nb][0];
        float sBt = sB + rsum[nb][1];
        float4 hd = *(const float4*)&h[(size_t)p * D + 4 * f4];
        float4 r;
        r.x = acc.x + o.x - sAt * hd.x + sBt;
        r.y = acc.y + o.y - sAt * hd.y + sBt;
        r.z = acc.z + o.z - sAt * hd.z + sBt;
        r.w = acc.w + o.w - sAt * hd.w + sBt;
        *(float4*)&aggr[(size_t)p * D + 4 * f4] = r;
    }
}

// ------------- node transform + ReLU + LayerNorm + residual --------------------------
// MFMA split-f16 GEMM: one wave owns a 16x128 output tile; no LDS, no barriers.
// 16-row tiles -> 783 blocks = 3132 waves (~3 waves/SIMD) vs 32-row's 1.5/SIMD:
// the K-loop's 18 global loads per step are latency-exposed at low occupancy.
__global__ __launch_bounds__(256) void k_node(const float* __restrict__ aggr,
                                              const float* __restrict__ hprev,
                                              const float* __restrict__ Wg,   // node_W + l*NT*D*D
                                              const float* __restrict__ bg,   // node_b + l*NT*D
                                              const float* __restrict__ lng,
                                              const float* __restrict__ lnb,
                                              const int* __restrict__ meta,
                                              float* __restrict__ hnext) {
    int wid  = threadIdx.x >> 6;
    int lane = threadIdx.x & 63;
    int w0 = (blockIdx.x * 4 + wid) * 16;          // first row of this wave's tile
    if (w0 >= NPAD) return;
    int l15 = lane & 15, lg = lane >> 4;
    int tt = (w0 >= meta[3]) ? 1 : 0;              // meta[3] is 64-aligned, w0 is 16-aligned
    const float* W = Wg + (size_t)tt * D * D;

    f32x4 acc[8];
#pragma unroll
    for (int j = 0; j < 8; j++) acc[j] = (f32x4){0.f, 0.f, 0.f, 0.f};

#pragma unroll 1
    for (int ks = 0; ks < 4; ks++) {
        int kb = ks * 32 + 8 * lg;                 // float offset within row
        float4 rA[2], rB[8][2];
        {
            const float* pa = aggr + (size_t)(w0 + l15) * D + kb;
            rA[0] = *(const float4*)pa;
            rA[1] = *(const float4*)(pa + 4);
        }
#pragma unroll
        for (int j = 0; j < 8; j++) {
            const float* pb = W + (size_t)(16 * j + l15) * D + kb;
            rB[j][0] = *(const float4*)pb;
            rB[j][1] = *(const float4*)(pb + 4);
        }
        f16x8 ahi, alo;
        cvt8(rA[0], rA[1], ahi, alo);
#pragma unroll
        for (int j = 0; j < 8; j++) {
            f16x8 bhi, blo;
            cvt8(rB[j][0], rB[j][1], bhi, blo);
            acc[j] = __builtin_amdgcn_mfma_f32_16x16x32_f16(ahi, bhi, acc[j], 0, 0, 0);
            acc[j] = __builtin_amdgcn_mfma_f32_16x16x32_f16(alo, bhi, acc[j], 0, 0, 0);
            acc[j] = __builtin_amdgcn_mfma_f32_16x16x32_f16(ahi, blo, acc[j], 0, 0, 0);
        }
    }

    // epilogue: bias + relu + LN (wave-local: full 128-wide row lives in one 16-lane group) + residual
    float bv[8], gv[8], bb[8];
#pragma unroll
    for (int j = 0; j < 8; j++) {
        int col = 16 * j + l15;
        bv[j] = bg[tt * D + col];
        gv[j] = lng[col];
        bb[j] = lnb[col];
    }
#pragma unroll
    for (int j = 0; j < 8; j++)
#pragma unroll
        for (int r = 0; r < 4; r++)
            acc[j][r] = fmaxf(acc[j][r] + bv[j], 0.f);

    float mu[4], rs[4];
#pragma unroll
    for (int r = 0; r < 4; r++) {
        float s = 0.f, s2 = 0.f;
#pragma unroll
        for (int j = 0; j < 8; j++) { float v = acc[j][r]; s += v; s2 += v * v; }
#pragma unroll
        for (int m = 1; m < 16; m <<= 1) { s += __shfl_xor(s, m); s2 += __shfl_xor(s2, m); }
        float mm = s * (1.f / 128.f);
        mu[r] = mm;
        rs[r] = rsqrtf(s2 * (1.f / 128.f) - mm * mm + 1e-5f);
    }

#pragma unroll
    for (int r = 0; r < 4; r++) {
        int row = w0 + 4 * lg + r;
#pragma unroll
        for (int j = 0; j < 8; j++) {
            int col = 16 * j + l15;
            float v = (acc[j][r] - mu[r]) * rs[r] * gv[j] + bb[j]
                      + hprev[(size_t)row * D + col];
            hnext[(size_t)row * D + col] = v;
        }
    }
}

// ------------- final FC with un-permute (same MFMA structure, scatter epilogue) -------------
__global__ __launch_bounds__(256) void k_fc(const float* __restrict__ hin,
                                            const float* __restrict__ W,
                                            const float* __restrict__ bias,
                                            const int* __restrict__ inv,
                                            float* __restrict__ out) {
    int wid  = threadIdx.x >> 6;
    int lane = threadIdx.x & 63;
    int w0 = (blockIdx.x * 4 + wid) * 16;
    if (w0 >= NPAD) return;
    int l15 = lane & 15, lg = lane >> 4;

    f32x4 acc[8];
#pragma unroll
    for (int j = 0; j < 8; j++) acc[j] = (f32x4){0.f, 0.f, 0.f, 0.f};

#pragma unroll 1
    for (int ks = 0; ks < 4; ks++) {
        int kb = ks * 32 + 8 * lg;
        float4 rA[2], rB[8][2];
        {
            const float* pa = hin + (size_t)(w0 + l15) * D + kb;
            rA[0] = *(const float4*)pa;
            rA[1] = *(const float4*)(pa + 4);
        }
#pragma unroll
        for (int j = 0; j < 8; j++) {
            const float* pb = W + (size_t)(16 * j + l15) * D + kb;
            rB[j][0] = *(const float4*)pb;
            rB[j][1] = *(const float4*)(pb + 4);
        }
        f16x8 ahi, alo;
        cvt8(rA[0], rA[1], ahi, alo);
#pragma unroll
        for (int j = 0; j < 8; j++) {
            f16x8 bhi, blo;
            cvt8(rB[j][0], rB[j][1], bhi, blo);
            acc[j] = __builtin_amdgcn_mfma_f32_16x16x32_f16(ahi, bhi, acc[j], 0, 0, 0);
            acc[j] = __builtin_amdgcn_mfma_f32_16x16x32_f16(alo, bhi, acc[j], 0, 0, 0);
            acc[j] = __builtin_amdgcn_mfma_f32_16x16x32_f16(ahi, blo, acc[j], 0, 0, 0);
        }
    }

    float bv[8];
#pragma unroll
    for (int j = 0; j < 8; j++) bv[j] = bias[16 * j + l15];

#pragma unroll
    for (int r = 0; r < 4; r++) {
        int row = w0 + 4 * lg + r;
        int orig = inv[row];
        if (orig >= 0) {
#pragma unroll
            for (int j = 0; j < 8; j++)
                out[(size_t)orig * D + 16 * j + l15] = acc[j][r] + bv[j];
        }
    }
}

extern "C" void kernel_launch(void* const* d_in, const int* in_sizes, int n_in,
                              void* d_out, int out_size, void* d_ws, size_t ws_size,
                              hipStream_t stream) {
    const float* x         = (const float*)d_in[0];
    const float* edge_attr = (const float*)d_in[1];
    const float* node_W    = (const float*)d_in[2];
    const float* node_b    = (const float*)d_in[3];
    const float* edge_W    = (const float*)d_in[4];
    const float* edge_b    = (const float*)d_in[5];
    const float* emb       = (const float*)d_in[6];
    const float* ln_g      = (const float*)d_in[7];
    const float* ln_b      = (const float*)d_in[8];
    const float* fc_W      = (const float*)d_in[9];
    const float* fc_b      = (const float*)d_in[10];
    const int*   edge_index = (const int*)d_in[11];
    const int*   node_type  = (const int*)d_in[12];
    const int*   edge_type  = (const int*)d_in[13];
    float* out = (float*)d_out;

    char* w = (char*)d_ws;
    auto alloc = [&](size_t bytes) {
        void* p = (void*)w;
        w += (bytes + 255) & ~(size_t)255;
        return p;
    };
    float*  P     = (float*)alloc((size_t)NPAD * D * 4);   // permuted x / layer buffers
    float*  Q     = (float*)alloc((size_t)NPAD * D * 4);
    float*  G     = (float*)alloc((size_t)NPAD * D * 4);   // aggr
    float4* esort = (float4*)alloc((size_t)EE * 32);
    int*    pos   = (int*)alloc((size_t)NN * 4);
    int*    inv   = (int*)alloc((size_t)NPAD * 4);
    int*    deg   = (int*)alloc((size_t)NN * 4);
    int*    offs  = (int*)alloc((size_t)NN * 4);
    int*    cur   = (int*)alloc((size_t)NN * 4);
    int*    bsum  = (int*)alloc(256 * 4);
    int*    boff  = (int*)alloc(256 * 4);
    int*    pc    = (int*)alloc(256 * 4);
    int*    po    = (int*)alloc(256 * 4);
    int*    meta  = (int*)alloc(8 * 4);

    hipMemsetAsync(deg, 0, (size_t)NN * 4, stream);
    hipMemsetAsync(inv, 0xFF, (size_t)NPAD * 4, stream);   // -1 = "gap row", k_fc skips

    k_pcount<<<NB, 256, 0, stream>>>(node_type, pc);
    k_pscan<<<1, 256, 0, stream>>>(pc, po, meta);
    k_passign<<<NB, 256, 0, stream>>>(node_type, po, meta, pos, inv);
    k_permx<<<(NN * 32 + 255) / 256, 256, 0, stream>>>(x, pos, P);

    k_hist<<<(EE + 255) / 256, 256, 0, stream>>>(edge_index + EE, deg);
    k_scan_bsum<<<NB, 256, 0, stream>>>(deg, bsum);
    k_scan_boff<<<1, 256, 0, stream>>>(bsum, boff);
    k_scan_offs<<<NB, 256, 0, stream>>>(deg, boff, offs, cur);
    k_edge<<<(EE + 255) / 256, 256, 0, stream>>>(edge_attr, edge_W, edge_b, emb,
                                                 edge_index, edge_type, pos, cur, esort);

    // layer rotation: P -> Q -> P -> Q   (in, out per layer)
    const float* hin = P;
    float* outs[LL] = {Q, P, Q};
    for (int l = 0; l < LL; l++) {
        k_gather<<<NN / 2, 256, 0, stream>>>(hin, offs, deg, pos, esort, l, G);
        k_node<<<NBLK16, 256, 0, stream>>>(G, hin,
                                           node_W + (size_t)l * NT * D * D,
                                           node_b + (size_t)l * NT * D,
                                           ln_g + (size_t)l * D,
                                           ln_b + (size_t)l * D,
                                           meta, outs[l]);
        hin = outs[l];
    }
    k_fc<<<NBLK16, 256, 0, stream>>>(hin, fc_W, fc_b, inv, out);
}

// Round 7
// 601.277 us; speedup vs baseline: 1.0361x; 1.0361x over previous
//
#include <hip/hip_runtime.h>
#include <math.h>

#define NN 50000
#define EE 800000
#define D 128
#define EDIM 32
#define LL 3
#define NT 2
#define ET 3
#define NB 196       // ceil(NN/256)
#define NPAD 50080   // >= align64(c0) + c1 for any split; multiple of 32
#define NTILE 1565   // NPAD/32 (32-row wave tiles)
#define NBLKM 392    // ceil(NTILE/4), 4 waves/block

typedef _Float16 f16x8 __attribute__((ext_vector_type(8)));
typedef float f32x4 __attribute__((ext_vector_type(4)));

// split 8 consecutive fp32 into hi/lo f16 halves (hi + lo == x to ~2^-21 rel)
__device__ __forceinline__ void cvt8(const float4 u, const float4 v, f16x8& hi, f16x8& lo) {
    float x[8] = {u.x, u.y, u.z, u.w, v.x, v.y, v.z, v.w};
#pragma unroll
    for (int e = 0; e < 8; e++) {
        _Float16 h = (_Float16)x[e];
        hi[e] = h;
        lo[e] = (_Float16)(x[e] - (float)h);
    }
}

// ---------------- node-type permutation (deterministic, scan-based) ----------------
// packed counts: low 16 = type0, high 16 = type1 (totals <= 50000 < 65536)
__global__ __launch_bounds__(256) void k_pcount(const int* __restrict__ nt, int* __restrict__ pc) {
    __shared__ int s[256];
    int d = blockIdx.x * 256 + threadIdx.x;
    int ind = 0;
    if (d < NN) ind = (nt[d] == 0) ? 1 : 0x10000;
    s[threadIdx.x] = ind;
    __syncthreads();
    for (int st = 128; st; st >>= 1) {
        if (threadIdx.x < st) s[threadIdx.x] += s[threadIdx.x + st];
        __syncthreads();
    }
    if (threadIdx.x == 0) pc[blockIdx.x] = s[0];
}

__global__ __launch_bounds__(256) void k_pscan(const int* __restrict__ pc, int* __restrict__ po,
                                               int* __restrict__ meta) {
    __shared__ int s[256];
    int t = threadIdx.x;
    int v = (t < NB) ? pc[t] : 0;
    s[t] = v;
    __syncthreads();
    for (int st = 1; st < 256; st <<= 1) {
        int add = (t >= st) ? s[t - st] : 0;
        __syncthreads();
        s[t] += add;
        __syncthreads();
    }
    if (t < NB) po[t] = s[t] - v;                     // exclusive packed block offsets
    if (t == 0) {
        int tot = s[255];
        meta[3] = ((tot & 0xffff) + 63) & ~63;        // aligned base for type-1 region
    }
}

__global__ __launch_bounds__(256) void k_passign(const int* __restrict__ nt, const int* __restrict__ po,
                                                 const int* __restrict__ meta,
                                                 int* __restrict__ pos, int* __restrict__ inv) {
    __shared__ int s[256];
    int t = threadIdx.x;
    int d = blockIdx.x * 256 + t;
    int ty = (d < NN) ? nt[d] : -1;
    int ind = (ty == 0) ? 1 : ((ty == 1) ? 0x10000 : 0);
    s[t] = ind;
    __syncthreads();
    for (int st = 1; st < 256; st <<= 1) {
        int add = (t >= st) ? s[t - st] : 0;
        __syncthreads();
        s[t] += add;
        __syncthreads();
    }
    if (d >= NN) return;
    int excl = s[t] - ind;
    int pop = po[blockIdx.x];
    int p;
    if (ty == 0) p = (pop & 0xffff) + (excl & 0xffff);
    else         p = meta[3] + (pop >> 16) + (excl >> 16);
    pos[d] = p;
    inv[p] = d;
}

__global__ __launch_bounds__(256) void k_permx(const float* __restrict__ x, const int* __restrict__ pos,
                                               float* __restrict__ h0) {
    int flat = blockIdx.x * 256 + threadIdx.x;
    if (flat >= NN * 32) return;
    int d = flat >> 5, f4 = flat & 31;
    int p = pos[d];
    ((float4*)h0)[(size_t)p * 32 + f4] = ((const float4*)x)[(size_t)d * 32 + f4];
}

// ---------------- histogram of dst ----------------
__global__ __launch_bounds__(256) void k_hist(const int* __restrict__ dst, int* __restrict__ deg) {
    int e = blockIdx.x * 256 + threadIdx.x;
    if (e < EE) atomicAdd(&deg[dst[e]], 1);
}

// ---------------- 2-level exclusive scan ----------------
__global__ __launch_bounds__(256) void k_scan_bsum(const int* __restrict__ deg, int* __restrict__ bsum) {
    __shared__ int s[256];
    int t = threadIdx.x;
    int d = blockIdx.x * 256 + t;
    s[t] = (d < NN) ? deg[d] : 0;
    __syncthreads();
    for (int st = 128; st > 0; st >>= 1) {
        if (t < st) s[t] += s[t + st];
        __syncthreads();
    }
    if (t == 0) bsum[blockIdx.x] = s[0];
}

__global__ __launch_bounds__(256) void k_scan_boff(const int* __restrict__ bsum, int* __restrict__ boff) {
    __shared__ int s[256];
    int t = threadIdx.x;
    s[t] = (t < NB) ? bsum[t] : 0;
    __syncthreads();
    for (int st = 1; st < 256; st <<= 1) {
        int add = (t >= st) ? s[t - st] : 0;
        __syncthreads();
        s[t] += add;
        __syncthreads();
    }
    if (t < NB) boff[t] = (t == 0) ? 0 : s[t - 1];
}

__global__ __launch_bounds__(256) void k_scan_offs(const int* __restrict__ deg, const int* __restrict__ boff,
                                                   int* __restrict__ offs, int* __restrict__ cur) {
    __shared__ int s[256];
    int t = threadIdx.x;
    int d = blockIdx.x * 256 + t;
    int v = (d < NN) ? deg[d] : 0;
    s[t] = v;
    __syncthreads();
    for (int st = 1; st < 256; st <<= 1) {
        int add = (t >= st) ? s[t - st] : 0;
        __syncthreads();
        s[t] += add;
        __syncthreads();
    }
    if (d < NN) {
        int excl = s[t] - v + boff[blockIdx.x];
        offs[d] = excl;
        cur[d]  = excl;
    }
}

// ------------- per-edge scalars (all 3 layers) packed + scattered into dst-sorted order -------------
// Weights repacked in LDS as w8[tt][c][8] (6 used: (l,wi) pairs), per-tt stride 264 floats so
// the 3 tt-groups hit distinct banks. Inner loop: 1 ds_read_b128 + 1 ds_read_b64 per c
// (64 LDS instrs/thread vs 192 with the row-major layout -> ~2/3 of the LDS-pipe time removed).
__global__ __launch_bounds__(256) void k_edge(const float* __restrict__ edge_attr,
                                              const float* __restrict__ edge_W,
                                              const float* __restrict__ edge_b,
                                              const float* __restrict__ emb,
                                              const int* __restrict__ ei,
                                              const int* __restrict__ etype,
                                              const int* __restrict__ pos,
                                              int* __restrict__ cur,
                                              float4* __restrict__ esort) {
    __shared__ float w8[3 * 264 + 8];   // [tt][c][8], stride 264 per tt
    __shared__ float ebd[18];           // emb·eW + eb, indexed (l*ET+tt)*2+wi
    int t0 = threadIdx.x;
    for (int i = t0; i < LL * ET * 2 * EDIM; i += 256) {
        int l  = i / 192;          // 192 = ET*2*EDIM
        int r1 = i % 192;
        int tt = r1 / 64;          // 64 = 2*EDIM
        int r2 = r1 % 64;
        int wi = r2 / 32;
        int c  = r2 % 32;
        w8[tt * 264 + c * 8 + l * 2 + wi] = edge_W[i];
    }
    __syncthreads();
    if (t0 < 18) {
        int l = t0 / (ET * 2);
        int rem = t0 % (ET * 2);
        int tt = rem / 2;
        int wi = rem % 2;
        float sum = edge_b[t0];
        const float* em = emb + (l * ET + tt) * EDIM;
        for (int c = 0; c < EDIM; c++) sum += em[c] * w8[tt * 264 + c * 8 + l * 2 + wi];
        ebd[t0] = sum;
    }
    __syncthreads();
    int e = blockIdx.x * 256 + t0;
    if (e >= EE) return;

    float a[EDIM];
    const float4* ap = (const float4*)(edge_attr + (size_t)e * EDIM);
#pragma unroll
    for (int i = 0; i < EDIM / 4; i++) {
        float4 v = ap[i];
        a[4 * i + 0] = v.x; a[4 * i + 1] = v.y; a[4 * i + 2] = v.z; a[4 * i + 3] = v.w;
    }
    int tt = etype[e];
    float dir  = a[EDIM - 2];
    float pump = a[EDIM - 1];
    float sign = dir * 2.f - 1.f;
    float speed = pump * (dir > 0.f ? dir : 1.f);
    int src = ei[e];
    int dst = ei[EE + e];
    int sp = pos[src];
    int p = atomicAdd(&cur[dst], 1);

    float r[6];
#pragma unroll
    for (int l = 0; l < LL; l++) {
        r[2 * l + 0] = ebd[(l * ET + tt) * 2 + 0];
        r[2 * l + 1] = ebd[(l * ET + tt) * 2 + 1];
    }
    const float* wp = w8 + tt * 264;
#pragma unroll
    for (int c = 0; c < EDIM; c++) {
        float4 p0 = *(const float4*)(wp + 8 * c);
        float2 p1 = *(const float2*)(wp + 8 * c + 4);
        float ac = a[c];
        r[0] += ac * p0.x; r[1] += ac * p0.y;
        r[2] += ac * p0.z; r[3] += ac * p0.w;
        r[4] += ac * p1.x; r[5] += ac * p1.y;
    }
    float Av[LL], Bv[LL];
#pragma unroll
    for (int l = 0; l < LL; l++) {
        float r0 = r[2 * l + 0], r1 = r[2 * l + 1];
        float gain = fmaxf(r0, 0.f) + log1pf(expf(-fabsf(r0)));   // stable softplus
        float bias = 0.f;
        if (tt == 1) { gain *= speed; bias = r1 * speed; }        // PUMP == 1
        Av[l] = sign * gain;
        Bv[l] = sign * bias;
    }
    float4 e0 = make_float4(__int_as_float(sp), Av[0], Av[1], Av[2]);
    float4 e1 = make_float4(Bv[0], Bv[1], Bv[2], 0.f);
    esort[(size_t)p * 2 + 0] = e0;
    esort[(size_t)p * 2 + 1] = e1;
}

// ------------- gather: aggr[pos[d]] = sum A*h[spos] - sA*h[pos[d]] + sB -------------
// 2 nodes / block; per node 4 edge-workers x 32 float4-lanes; 2 edges in flight per worker.
__global__ __launch_bounds__(256) void k_gather(const float* __restrict__ h,
                                                const int* __restrict__ offs,
                                                const int* __restrict__ deg,
                                                const int* __restrict__ pos,
                                                const float4* __restrict__ esort,
                                                int layer,
                                                float* __restrict__ aggr) {
    __shared__ float4 rbuf[2][32];
    __shared__ float  rsum[2][2];
    int local = threadIdx.x;
    int nb = local >> 7;                    // node within block
    int node = blockIdx.x * 2 + nb;
    int t = local & 127;
    int w = t >> 5;                         // worker 0..3
    int f4 = t & 31;                        // feature-quad lane
    int start = offs[node];
    int n = deg[node];
    int p = pos[node];

    float4 acc = make_float4(0.f, 0.f, 0.f, 0.f);
    float sA = 0.f, sB = 0.f;
    for (int k = w; k < n; k += 8) {
        int k2 = k + 4;
        bool ok2 = (k2 < n);
        size_t i1 = (size_t)(start + k) * 2;
        size_t i2 = ok2 ? (size_t)(start + k2) * 2 : i1;
        float4 e0 = esort[i1];
        float4 e1 = esort[i1 + 1];
        float4 f0 = esort[i2];
        float4 f1 = esort[i2 + 1];
        int s1 = __float_as_int(e0.x);
        int s2 = __float_as_int(f0.x);
        float4 h1 = *(const float4*)&h[(size_t)s1 * D + 4 * f4];
        float4 h2 = *(const float4*)&h[(size_t)s2 * D + 4 * f4];
        float A1 = (layer == 0) ? e0.y : ((layer == 1) ? e0.z : e0.w);
        float B1 = (layer == 0) ? e1.x : ((layer == 1) ? e1.y : e1.z);
        float A2 = (layer == 0) ? f0.y : ((layer == 1) ? f0.z : f0.w);
        float B2 = (layer == 0) ? f1.x : ((layer == 1) ? f1.y : f1.z);
        if (!ok2) { A2 = 0.f; B2 = 0.f; }
        acc.x += A1 * h1.x + A2 * h2.x;
        acc.y += A1 * h1.y + A2 * h2.y;
        acc.z += A1 * h1.z + A2 * h2.z;
        acc.w += A1 * h1.w + A2 * h2.w;
        sA += A1 + A2; sB += B1 + B2;
    }
    // combine worker pairs within wave (lanes l and l^32)
    acc.x += __shfl_xor(acc.x, 32); acc.y += __shfl_xor(acc.y, 32);
    acc.z += __shfl_xor(acc.z, 32); acc.w += __shfl_xor(acc.w, 32);
    sA += __shfl_xor(sA, 32); sB += __shfl_xor(sB, 32);
    // cross-wave combine via LDS: upper wave of each node writes, lower reads
    if (((local >> 6) & 1) == 1 && (t & 63) < 32) {
        rbuf[nb][f4] = acc;
        if (f4 == 0) { rsum[nb][0] = sA; rsum[nb][1] = sB; }
    }
    __syncthreads();
    if (((local >> 6) & 1) == 0 && (t & 63) < 32) {
        float4 o = rbuf[nb][f4];
        float sAt = sA + rsum[nb][0];
        float sBt = sB + rsum[nb][1];
        float4 hd = *(const float4*)&h[(size_t)p * D + 4 * f4];
        float4 r;
        r.x = acc.x + o.x - sAt * hd.x + sBt;
        r.y = acc.y + o.y - sAt * hd.y + sBt;
        r.z = acc.z + o.z - sAt * hd.z + sBt;
        r.w = acc.w + o.w - sAt * hd.w + sBt;
        *(float4*)&aggr[(size_t)p * D + 4 * f4] = r;
    }
}

// ------------- node transform + ReLU + LayerNorm + residual --------------------------
// MFMA split-f16 GEMM, SWAPPED operands: A = W (M=channels), B = aggr (N=nodes).
// D[ch][node]: node = lane&15, lane's 4 acc regs = 4 CONSECUTIVE channels (16j+4*lg+r)
// -> the whole epilogue (bias/LN/residual/store) runs on float4, 4x fewer VMEM instrs
// than the channel-on-lane layout. K-loop addressing identical to the proven kernel.
__global__ __launch_bounds__(256) void k_node(const float* __restrict__ aggr,
                                              const float* __restrict__ hprev,
                                              const float* __restrict__ Wg,   // node_W + l*NT*D*D
                                              const float* __restrict__ bg,   // node_b + l*NT*D
                                              const float* __restrict__ lng,
                                              const float* __restrict__ lnb,
                                              const int* __restrict__ meta,
                                              float* __restrict__ hnext) {
    int wid  = threadIdx.x >> 6;
    int lane = threadIdx.x & 63;
    int w0 = (blockIdx.x * 4 + wid) * 32;          // first node of this wave's tile
    if (w0 >= NPAD) return;
    int l15 = lane & 15, lg = lane >> 4;
    int tt = (w0 >= meta[3]) ? 1 : 0;              // meta[3] is 64-aligned, w0 is 32-aligned
    const float* W = Wg + (size_t)tt * D * D;

    f32x4 acc[2][8];                               // [node-group][channel-tile]
#pragma unroll
    for (int i = 0; i < 2; i++)
#pragma unroll
        for (int j = 0; j < 8; j++) acc[i][j] = (f32x4){0.f, 0.f, 0.f, 0.f};

#pragma unroll 1
    for (int ks = 0; ks < 4; ks++) {
        int kb = ks * 32 + 8 * lg;                 // float offset within row
        float4 rA[2][2], rB[8][2];
#pragma unroll
        for (int i = 0; i < 2; i++) {
            const float* p = aggr + (size_t)(w0 + 16 * i + l15) * D + kb;
            rA[i][0] = *(const float4*)p;
            rA[i][1] = *(const float4*)(p + 4);
        }
#pragma unroll
        for (int j = 0; j < 8; j++) {
            const float* p = W + (size_t)(16 * j + l15) * D + kb;
            rB[j][0] = *(const float4*)p;
            rB[j][1] = *(const float4*)(p + 4);
        }
        f16x8 ahi[2], alo[2];
#pragma unroll
        for (int i = 0; i < 2; i++) cvt8(rA[i][0], rA[i][1], ahi[i], alo[i]);
#pragma unroll
        for (int j = 0; j < 8; j++) {
            f16x8 whi, wlo;
            cvt8(rB[j][0], rB[j][1], whi, wlo);
#pragma unroll
            for (int i = 0; i < 2; i++) {
                acc[i][j] = __builtin_amdgcn_mfma_f32_16x16x32_f16(whi, ahi[i], acc[i][j], 0, 0, 0);
                acc[i][j] = __builtin_amdgcn_mfma_f32_16x16x32_f16(wlo, ahi[i], acc[i][j], 0, 0, 0);
                acc[i][j] = __builtin_amdgcn_mfma_f32_16x16x32_f16(whi, alo[i], acc[i][j], 0, 0, 0);
            }
        }
    }

    // epilogue: lane owns node n_i = w0+16i+l15, channels ch = 16j+4*lg+{0..3} (float4-contiguous)
    int chb = 4 * lg;
    float4 bv[8], gv[8], lb[8];
#pragma unroll
    for (int j = 0; j < 8; j++) {
        int ch = 16 * j + chb;
        bv[j] = *(const float4*)&bg[tt * D + ch];
        gv[j] = *(const float4*)&lng[ch];
        lb[j] = *(const float4*)&lnb[ch];
    }
#pragma unroll
    for (int i = 0; i < 2; i++) {
#pragma unroll
        for (int j = 0; j < 8; j++) {
            acc[i][j][0] = fmaxf(acc[i][j][0] + bv[j].x, 0.f);
            acc[i][j][1] = fmaxf(acc[i][j][1] + bv[j].y, 0.f);
            acc[i][j][2] = fmaxf(acc[i][j][2] + bv[j].z, 0.f);
            acc[i][j][3] = fmaxf(acc[i][j][3] + bv[j].w, 0.f);
        }
    }

    // LN per node: this lane's 32 channels + lanes {l^16, l^32} hold the other 96
    float mu[2], rs[2];
#pragma unroll
    for (int i = 0; i < 2; i++) {
        float s = 0.f, s2 = 0.f;
#pragma unroll
        for (int j = 0; j < 8; j++)
#pragma unroll
            for (int r = 0; r < 4; r++) { float v = acc[i][j][r]; s += v; s2 += v * v; }
        s += __shfl_xor(s, 16); s2 += __shfl_xor(s2, 16);
        s += __shfl_xor(s, 32); s2 += __shfl_xor(s2, 32);
        float mm = s * (1.f / 128.f);
        mu[i] = mm;
        rs[i] = rsqrtf(s2 * (1.f / 128.f) - mm * mm + 1e-5f);
    }

#pragma unroll
    for (int i = 0; i < 2; i++) {
        int n = w0 + 16 * i + l15;
        const float* hp = hprev + (size_t)n * D;
        float* hn = hnext + (size_t)n * D;
#pragma unroll
        for (int j = 0; j < 8; j++) {
            int ch = 16 * j + chb;
            float4 hv = *(const float4*)&hp[ch];
            float4 o;
            o.x = (acc[i][j][0] - mu[i]) * rs[i] * gv[j].x + lb[j].x + hv.x;
            o.y = (acc[i][j][1] - mu[i]) * rs[i] * gv[j].y + lb[j].y + hv.y;
            o.z = (acc[i][j][2] - mu[i]) * rs[i] * gv[j].z + lb[j].z + hv.z;
            o.w = (acc[i][j][3] - mu[i]) * rs[i] * gv[j].w + lb[j].w + hv.w;
            *(float4*)&hn[ch] = o;
        }
    }
}

// ------------- final FC with un-permute (same swapped-operand structure, float4 scatter) -------------
__global__ __launch_bounds__(256) void k_fc(const float* __restrict__ hin,
                                            const float* __restrict__ W,
                                            const float* __restrict__ bias,
                                            const int* __restrict__ inv,
                                            float* __restrict__ out) {
    int wid  = threadIdx.x >> 6;
    int lane = threadIdx.x & 63;
    int w0 = (blockIdx.x * 4 + wid) * 32;
    if (w0 >= NPAD) return;
    int l15 = lane & 15, lg = lane >> 4;

    f32x4 acc[2][8];
#pragma unroll
    for (int i = 0; i < 2; i++)
#pragma unroll
        for (int j = 0; j < 8; j++) acc[i][j] = (f32x4){0.f, 0.f, 0.f, 0.f};

#pragma unroll 1
    for (int ks = 0; ks < 4; ks++) {
        int kb = ks * 32 + 8 * lg;
        float4 rA[2][2], rB[8][2];
#pragma unroll
        for (int i = 0; i < 2; i++) {
            const float* p = hin + (size_t)(w0 + 16 * i + l15) * D + kb;
            rA[i][0] = *(const float4*)p;
            rA[i][1] = *(const float4*)(p + 4);
        }
#pragma unroll
        for (int j = 0; j < 8; j++) {
            const float* p = W + (size_t)(16 * j + l15) * D + kb;
            rB[j][0] = *(const float4*)p;
            rB[j][1] = *(const float4*)(p + 4);
        }
        f16x8 ahi[2], alo[2];
#pragma unroll
        for (int i = 0; i < 2; i++) cvt8(rA[i][0], rA[i][1], ahi[i], alo[i]);
#pragma unroll
        for (int j = 0; j < 8; j++) {
            f16x8 whi, wlo;
            cvt8(rB[j][0], rB[j][1], whi, wlo);
#pragma unroll
            for (int i = 0; i < 2; i++) {
                acc[i][j] = __builtin_amdgcn_mfma_f32_16x16x32_f16(whi, ahi[i], acc[i][j], 0, 0, 0);
                acc[i][j] = __builtin_amdgcn_mfma_f32_16x16x32_f16(wlo, ahi[i], acc[i][j], 0, 0, 0);
                acc[i][j] = __builtin_amdgcn_mfma_f32_16x16x32_f16(whi, alo[i], acc[i][j], 0, 0, 0);
            }
        }
    }

    int chb = 4 * lg;
    float4 bv[8];
#pragma unroll
    for (int j = 0; j < 8; j++) bv[j] = *(const float4*)&bias[16 * j + chb];

#pragma unroll
    for (int i = 0; i < 2; i++) {
        int n = w0 + 16 * i + l15;
        int orig = inv[n];
        if (orig >= 0) {
            float* op = out + (size_t)orig * D;
#pragma unroll
            for (int j = 0; j < 8; j++) {
                int ch = 16 * j + chb;
                float4 o;
                o.x = acc[i][j][0] + bv[j].x;
                o.y = acc[i][j][1] + bv[j].y;
                o.z = acc[i][j][2] + bv[j].z;
                o.w = acc[i][j][3] + bv[j].w;
                *(float4*)&op[ch] = o;
            }
        }
    }
}

extern "C" void kernel_launch(void* const* d_in, const int* in_sizes, int n_in,
                              void* d_out, int out_size, void* d_ws, size_t ws_size,
                              hipStream_t stream) {
    const float* x         = (const float*)d_in[0];
    const float* edge_attr = (const float*)d_in[1];
    const float* node_W    = (const float*)d_in[2];
    const float* node_b    = (const float*)d_in[3];
    const float* edge_W    = (const float*)d_in[4];
    const float* edge_b    = (const float*)d_in[5];
    const float* emb       = (const float*)d_in[6];
    const float* ln_g      = (const float*)d_in[7];
    const float* ln_b      = (const float*)d_in[8];
    const float* fc_W      = (const float*)d_in[9];
    const float* fc_b      = (const float*)d_in[10];
    const int*   edge_index = (const int*)d_in[11];
    const int*   node_type  = (const int*)d_in[12];
    const int*   edge_type  = (const int*)d_in[13];
    float* out = (float*)d_out;

    char* w = (char*)d_ws;
    auto alloc = [&](size_t bytes) {
        void* p = (void*)w;
        w += (bytes + 255) & ~(size_t)255;
        return p;
    };
    float*  P     = (float*)alloc((size_t)NPAD * D * 4);   // permuted x / layer buffers
    float*  Q     = (float*)alloc((size_t)NPAD * D * 4);
    float*  G     = (float*)alloc((size_t)NPAD * D * 4);   // aggr
    float4* esort = (float4*)alloc((size_t)EE * 32);
    int*    pos   = (int*)alloc((size_t)NN * 4);
    int*    inv   = (int*)alloc((size_t)NPAD * 4);
    int*    deg   = (int*)alloc((size_t)NN * 4);
    int*    offs  = (int*)alloc((size_t)NN * 4);
    int*    cur   = (int*)alloc((size_t)NN * 4);
    int*    bsum  = (int*)alloc(256 * 4);
    int*    boff  = (int*)alloc(256 * 4);
    int*    pc    = (int*)alloc(256 * 4);
    int*    po    = (int*)alloc(256 * 4);
    int*    meta  = (int*)alloc(8 * 4);

    hipMemsetAsync(deg, 0, (size_t)NN * 4, stream);
    hipMemsetAsync(inv, 0xFF, (size_t)NPAD * 4, stream);   // -1 = "gap row", k_fc skips

    k_pcount<<<NB, 256, 0, stream>>>(node_type, pc);
    k_pscan<<<1, 256, 0, stream>>>(pc, po, meta);
    k_passign<<<NB, 256, 0, stream>>>(node_type, po, meta, pos, inv);
    k_permx<<<(NN * 32 + 255) / 256, 256, 0, stream>>>(x, pos, P);

    k_hist<<<(EE + 255) / 256, 256, 0, stream>>>(edge_index + EE, deg);
    k_scan_bsum<<<NB, 256, 0, stream>>>(deg, bsum);
    k_scan_boff<<<1, 256, 0, stream>>>(bsum, boff);
    k_scan_offs<<<NB, 256, 0, stream>>>(deg, boff, offs, cur);
    k_edge<<<(EE + 255) / 256, 256, 0, stream>>>(edge_attr, edge_W, edge_b, emb,
                                                 edge_index, edge_type, pos, cur, esort);

    // layer rotation: P -> Q -> P -> Q   (in, out per layer)
    const float* hin = P;
    float* outs[LL] = {Q, P, Q};
    for (int l = 0; l < LL; l++) {
        k_gather<<<NN / 2, 256, 0, stream>>>(hin, offs, deg, pos, esort, l, G);
        k_node<<<NBLKM, 256, 0, stream>>>(G, hin,
                                          node_W + (size_t)l * NT * D * D,
                                          node_b + (size_t)l * NT * D,
                                          ln_g + (size_t)l * D,
                                          ln_b + (size_t)l * D,
                                          meta, outs[l]);
        hin = outs[l];
    }
    k_fc<<<NBLKM, 256, 0, stream>>>(hin, fc_W, fc_b, inv, out);
}

// Round 8
// 576.354 us; speedup vs baseline: 1.0809x; 1.0432x over previous
//
#include <hip/hip_runtime.h>
#include <math.h>

#define NN 50000
#define EE 800000
#define D 128
#define EDIM 32
#define LL 3
#define NT 2
#define ET 3
#define NB 196       // ceil(NN/256)
#define NPAD 50080   // >= align64(c0) + c1 for any split; multiple of 32
#define NTILE 1565   // NPAD/32 (32-row wave tiles)
#define NBLKM 392    // ceil(NTILE/4), 4 waves/block

typedef _Float16 f16x8 __attribute__((ext_vector_type(8)));
typedef float f32x4 __attribute__((ext_vector_type(4)));

// split 8 consecutive fp32 into hi/lo f16 halves (hi + lo == x to ~2^-21 rel)
__device__ __forceinline__ void cvt8(const float4 u, const float4 v, f16x8& hi, f16x8& lo) {
    float x[8] = {u.x, u.y, u.z, u.w, v.x, v.y, v.z, v.w};
#pragma unroll
    for (int e = 0; e < 8; e++) {
        _Float16 h = (_Float16)x[e];
        hi[e] = h;
        lo[e] = (_Float16)(x[e] - (float)h);
    }
}

// ---------------- node-type permutation (deterministic, scan-based) ----------------
// packed counts: low 16 = type0, high 16 = type1 (totals <= 50000 < 65536)
__global__ __launch_bounds__(256) void k_pcount(const int* __restrict__ nt, int* __restrict__ pc) {
    __shared__ int s[256];
    int d = blockIdx.x * 256 + threadIdx.x;
    int ind = 0;
    if (d < NN) ind = (nt[d] == 0) ? 1 : 0x10000;
    s[threadIdx.x] = ind;
    __syncthreads();
    for (int st = 128; st; st >>= 1) {
        if (threadIdx.x < st) s[threadIdx.x] += s[threadIdx.x + st];
        __syncthreads();
    }
    if (threadIdx.x == 0) pc[blockIdx.x] = s[0];
}

__global__ __launch_bounds__(256) void k_pscan(const int* __restrict__ pc, int* __restrict__ po,
                                               int* __restrict__ meta) {
    __shared__ int s[256];
    int t = threadIdx.x;
    int v = (t < NB) ? pc[t] : 0;
    s[t] = v;
    __syncthreads();
    for (int st = 1; st < 256; st <<= 1) {
        int add = (t >= st) ? s[t - st] : 0;
        __syncthreads();
        s[t] += add;
        __syncthreads();
    }
    if (t < NB) po[t] = s[t] - v;                     // exclusive packed block offsets
    if (t == 0) {
        int tot = s[255];
        meta[3] = ((tot & 0xffff) + 63) & ~63;        // aligned base for type-1 region
    }
}

__global__ __launch_bounds__(256) void k_passign(const int* __restrict__ nt, const int* __restrict__ po,
                                                 const int* __restrict__ meta,
                                                 int* __restrict__ pos, int* __restrict__ inv) {
    __shared__ int s[256];
    int t = threadIdx.x;
    int d = blockIdx.x * 256 + t;
    int ty = (d < NN) ? nt[d] : -1;
    int ind = (ty == 0) ? 1 : ((ty == 1) ? 0x10000 : 0);
    s[t] = ind;
    __syncthreads();
    for (int st = 1; st < 256; st <<= 1) {
        int add = (t >= st) ? s[t - st] : 0;
        __syncthreads();
        s[t] += add;
        __syncthreads();
    }
    if (d >= NN) return;
    int excl = s[t] - ind;
    int pop = po[blockIdx.x];
    int p;
    if (ty == 0) p = (pop & 0xffff) + (excl & 0xffff);
    else         p = meta[3] + (pop >> 16) + (excl >> 16);
    pos[d] = p;
    inv[p] = d;
}

__global__ __launch_bounds__(256) void k_permx(const float* __restrict__ x, const int* __restrict__ pos,
                                               float* __restrict__ h0) {
    int flat = blockIdx.x * 256 + threadIdx.x;
    if (flat >= NN * 32) return;
    int d = flat >> 5, f4 = flat & 31;
    int p = pos[d];
    ((float4*)h0)[(size_t)p * 32 + f4] = ((const float4*)x)[(size_t)d * 32 + f4];
}

// ---------------- histogram of dst ----------------
__global__ __launch_bounds__(256) void k_hist(const int* __restrict__ dst, int* __restrict__ deg) {
    int e = blockIdx.x * 256 + threadIdx.x;
    if (e < EE) atomicAdd(&deg[dst[e]], 1);
}

// ---------------- 2-level exclusive scan ----------------
__global__ __launch_bounds__(256) void k_scan_bsum(const int* __restrict__ deg, int* __restrict__ bsum) {
    __shared__ int s[256];
    int t = threadIdx.x;
    int d = blockIdx.x * 256 + t;
    s[t] = (d < NN) ? deg[d] : 0;
    __syncthreads();
    for (int st = 128; st > 0; st >>= 1) {
        if (t < st) s[t] += s[t + st];
        __syncthreads();
    }
    if (t == 0) bsum[blockIdx.x] = s[0];
}

__global__ __launch_bounds__(256) void k_scan_boff(const int* __restrict__ bsum, int* __restrict__ boff) {
    __shared__ int s[256];
    int t = threadIdx.x;
    s[t] = (t < NB) ? bsum[t] : 0;
    __syncthreads();
    for (int st = 1; st < 256; st <<= 1) {
        int add = (t >= st) ? s[t - st] : 0;
        __syncthreads();
        s[t] += add;
        __syncthreads();
    }
    if (t < NB) boff[t] = (t == 0) ? 0 : s[t - 1];
}

__global__ __launch_bounds__(256) void k_scan_offs(const int* __restrict__ deg, const int* __restrict__ boff,
                                                   int* __restrict__ offs, int* __restrict__ cur) {
    __shared__ int s[256];
    int t = threadIdx.x;
    int d = blockIdx.x * 256 + t;
    int v = (d < NN) ? deg[d] : 0;
    s[t] = v;
    __syncthreads();
    for (int st = 1; st < 256; st <<= 1) {
        int add = (t >= st) ? s[t - st] : 0;
        __syncthreads();
        s[t] += add;
        __syncthreads();
    }
    if (d < NN) {
        int excl = s[t] - v + boff[blockIdx.x];
        offs[d] = excl;
        cur[d]  = excl;
    }
}

// ------------- per-edge scalars (all 3 layers) packed + scattered into dst-sorted order -------------
// Weights repacked in LDS as w8[tt][c][8] (6 used: (l,wi) pairs), per-tt stride 264 floats so
// the 3 tt-groups hit distinct banks. Inner loop: 1 ds_read_b128 + 1 ds_read_b64 per c
// (64 LDS instrs/thread vs 192 row-major). Measured in R7: 73.5 -> 70.4 us, occupancy 41 -> 52%.
__global__ __launch_bounds__(256) void k_edge(const float* __restrict__ edge_attr,
                                              const float* __restrict__ edge_W,
                                              const float* __restrict__ edge_b,
                                              const float* __restrict__ emb,
                                              const int* __restrict__ ei,
                                              const int* __restrict__ etype,
                                              const int* __restrict__ pos,
                                              int* __restrict__ cur,
                                              float4* __restrict__ esort) {
    __shared__ float w8[3 * 264 + 8];   // [tt][c][8], stride 264 per tt
    __shared__ float ebd[18];           // emb·eW + eb, indexed (l*ET+tt)*2+wi
    int t0 = threadIdx.x;
    for (int i = t0; i < LL * ET * 2 * EDIM; i += 256) {
        int l  = i / 192;          // 192 = ET*2*EDIM
        int r1 = i % 192;
        int tt = r1 / 64;          // 64 = 2*EDIM
        int r2 = r1 % 64;
        int wi = r2 / 32;
        int c  = r2 % 32;
        w8[tt * 264 + c * 8 + l * 2 + wi] = edge_W[i];
    }
    __syncthreads();
    if (t0 < 18) {
        int l = t0 / (ET * 2);
        int rem = t0 % (ET * 2);
        int tt = rem / 2;
        int wi = rem % 2;
        float sum = edge_b[t0];
        const float* em = emb + (l * ET + tt) * EDIM;
        for (int c = 0; c < EDIM; c++) sum += em[c] * w8[tt * 264 + c * 8 + l * 2 + wi];
        ebd[t0] = sum;
    }
    __syncthreads();
    int e = blockIdx.x * 256 + t0;
    if (e >= EE) return;

    float a[EDIM];
    const float4* ap = (const float4*)(edge_attr + (size_t)e * EDIM);
#pragma unroll
    for (int i = 0; i < EDIM / 4; i++) {
        float4 v = ap[i];
        a[4 * i + 0] = v.x; a[4 * i + 1] = v.y; a[4 * i + 2] = v.z; a[4 * i + 3] = v.w;
    }
    int tt = etype[e];
    float dir  = a[EDIM - 2];
    float pump = a[EDIM - 1];
    float sign = dir * 2.f - 1.f;
    float speed = pump * (dir > 0.f ? dir : 1.f);
    int src = ei[e];
    int dst = ei[EE + e];
    int sp = pos[src];
    int p = atomicAdd(&cur[dst], 1);

    float r[6];
#pragma unroll
    for (int l = 0; l < LL; l++) {
        r[2 * l + 0] = ebd[(l * ET + tt) * 2 + 0];
        r[2 * l + 1] = ebd[(l * ET + tt) * 2 + 1];
    }
    const float* wp = w8 + tt * 264;
#pragma unroll
    for (int c = 0; c < EDIM; c++) {
        float4 p0 = *(const float4*)(wp + 8 * c);
        float2 p1 = *(const float2*)(wp + 8 * c + 4);
        float ac = a[c];
        r[0] += ac * p0.x; r[1] += ac * p0.y;
        r[2] += ac * p0.z; r[3] += ac * p0.w;
        r[4] += ac * p1.x; r[5] += ac * p1.y;
    }
    float Av[LL], Bv[LL];
#pragma unroll
    for (int l = 0; l < LL; l++) {
        float r0 = r[2 * l + 0], r1 = r[2 * l + 1];
        float gain = fmaxf(r0, 0.f) + log1pf(expf(-fabsf(r0)));   // stable softplus
        float bias = 0.f;
        if (tt == 1) { gain *= speed; bias = r1 * speed; }        // PUMP == 1
        Av[l] = sign * gain;
        Bv[l] = sign * bias;
    }
    float4 e0 = make_float4(__int_as_float(sp), Av[0], Av[1], Av[2]);
    float4 e1 = make_float4(Bv[0], Bv[1], Bv[2], 0.f);
    esort[(size_t)p * 2 + 0] = e0;
    esort[(size_t)p * 2 + 1] = e1;
}

// ------------- gather: aggr[pos[d]] = sum A*h[spos] - sA*h[pos[d]] + sB -------------
// 2 nodes / block; per node 4 edge-workers x 32 float4-lanes.
// 4 edges in flight per worker (stride 16 covers the average degree in one iteration):
// all record loads then all h-row loads are issued before the FMAs.
__global__ __launch_bounds__(256) void k_gather(const float* __restrict__ h,
                                                const int* __restrict__ offs,
                                                const int* __restrict__ deg,
                                                const int* __restrict__ pos,
                                                const float4* __restrict__ esort,
                                                int layer,
                                                float* __restrict__ aggr) {
    __shared__ float4 rbuf[2][32];
    __shared__ float  rsum[2][2];
    int local = threadIdx.x;
    int nb = local >> 7;                    // node within block
    int node = blockIdx.x * 2 + nb;
    int t = local & 127;
    int w = t >> 5;                         // worker 0..3
    int f4 = t & 31;                        // feature-quad lane
    int start = offs[node];
    int n = deg[node];
    int p = pos[node];

    float4 acc = make_float4(0.f, 0.f, 0.f, 0.f);
    float sA = 0.f, sB = 0.f;
    for (int k = w; k < n; k += 16) {
        float4 e0[4], e1[4];
#pragma unroll
        for (int u = 0; u < 4; u++) {
            int ku = k + 4 * u;
            size_t idx = (ku < n) ? (size_t)(start + ku) * 2 : (size_t)start * 2;
            e0[u] = esort[idx];
            e1[u] = esort[idx + 1];
        }
        float4 hv[4];
#pragma unroll
        for (int u = 0; u < 4; u++) {
            int s = __float_as_int(e0[u].x);
            hv[u] = *(const float4*)&h[(size_t)s * D + 4 * f4];
        }
#pragma unroll
        for (int u = 0; u < 4; u++) {
            int ku = k + 4 * u;
            float A = (layer == 0) ? e0[u].y : ((layer == 1) ? e0[u].z : e0[u].w);
            float B = (layer == 0) ? e1[u].x : ((layer == 1) ? e1[u].y : e1[u].z);
            if (ku >= n) { A = 0.f; B = 0.f; }
            acc.x += A * hv[u].x; acc.y += A * hv[u].y;
            acc.z += A * hv[u].z; acc.w += A * hv[u].w;
            sA += A; sB += B;
        }
    }
    // combine worker pairs within wave (lanes l and l^32)
    acc.x += __shfl_xor(acc.x, 32); acc.y += __shfl_xor(acc.y, 32);
    acc.z += __shfl_xor(acc.z, 32); acc.w += __shfl_xor(acc.w, 32);
    sA += __shfl_xor(sA, 32); sB += __shfl_xor(sB, 32);
    // cross-wave combine via LDS: upper wave of each node writes, lower reads
    if (((local >> 6) & 1) == 1 && (t & 63) < 32) {
        rbuf[nb][f4] = acc;
        if (f4 == 0) { rsum[nb][0] = sA; rsum[nb][1] = sB; }
    }
    __syncthreads();
    if (((local >> 6) & 1) == 0 && (t & 63) < 32) {
        float4 o = rbuf[nb][f4];
        float sAt = sA + rsum[nb][0];
        float sBt = sB + rsum[nb][1];
        float4 hd = *(const float4*)&h[(size_t)p * D + 4 * f4];
        float4 r;
        r.x = acc.x + o.x - sAt * hd.x + sBt;
        r.y = acc.y + o.y - sAt * hd.y + sBt;
        r.z = acc.z + o.z - sAt * hd.z + sBt;
        r.w = acc.w + o.w - sAt * hd.w + sBt;
        *(float4*)&aggr[(size_t)p * D + 4 * f4] = r;
    }
}

// ------------- node transform + ReLU + LayerNorm + residual --------------------------
// MFMA split-f16 GEMM: one wave owns a 32x128 output tile; no LDS, no barriers.
// FROZEN at the R3 form: 16-row tiles (R6) and swapped operands (R7) both measured worse.
__global__ __launch_bounds__(256) void k_node(const float* __restrict__ aggr,
                                              const float* __restrict__ hprev,
                                              const float* __restrict__ Wg,   // node_W + l*NT*D*D
                                              const float* __restrict__ bg,   // node_b + l*NT*D
                                              const float* __restrict__ lng,
                                              const float* __restrict__ lnb,
                                              const int* __restrict__ meta,
                                              float* __restrict__ hnext) {
    int wid  = threadIdx.x >> 6;
    int lane = threadIdx.x & 63;
    int w0 = (blockIdx.x * 4 + wid) * 32;          // first row of this wave's tile
    if (w0 >= NPAD) return;
    int l15 = lane & 15, lg = lane >> 4;
    int tt = (w0 >= meta[3]) ? 1 : 0;              // meta[3] is 64-aligned, w0 is 32-aligned
    const float* W = Wg + (size_t)tt * D * D;

    f32x4 acc[2][8];
#pragma unroll
    for (int i = 0; i < 2; i++)
#pragma unroll
        for (int j = 0; j < 8; j++) acc[i][j] = (f32x4){0.f, 0.f, 0.f, 0.f};

#pragma unroll 1
    for (int ks = 0; ks < 4; ks++) {
        int kb = ks * 32 + 8 * lg;                 // float offset within row
        float4 rA[2][2], rB[8][2];
#pragma unroll
        for (int i = 0; i < 2; i++) {
            const float* p = aggr + (size_t)(w0 + 16 * i + l15) * D + kb;
            rA[i][0] = *(const float4*)p;
            rA[i][1] = *(const float4*)(p + 4);
        }
#pragma unroll
        for (int j = 0; j < 8; j++) {
            const float* p = W + (size_t)(16 * j + l15) * D + kb;
            rB[j][0] = *(const float4*)p;
            rB[j][1] = *(const float4*)(p + 4);
        }
        f16x8 ahi[2], alo[2];
#pragma unroll
        for (int i = 0; i < 2; i++) cvt8(rA[i][0], rA[i][1], ahi[i], alo[i]);
#pragma unroll
        for (int j = 0; j < 8; j++) {
            f16x8 bhi, blo;
            cvt8(rB[j][0], rB[j][1], bhi, blo);
#pragma unroll
            for (int i = 0; i < 2; i++) {
                acc[i][j] = __builtin_amdgcn_mfma_f32_16x16x32_f16(ahi[i], bhi, acc[i][j], 0, 0, 0);
                acc[i][j] = __builtin_amdgcn_mfma_f32_16x16x32_f16(alo[i], bhi, acc[i][j], 0, 0, 0);
                acc[i][j] = __builtin_amdgcn_mfma_f32_16x16x32_f16(ahi[i], blo, acc[i][j], 0, 0, 0);
            }
        }
    }

    // epilogue: bias + relu + LN (wave-local: full 128-wide row lives in one 16-lane group) + residual
    float bv[8], gv[8], bb[8];
#pragma unroll
    for (int j = 0; j < 8; j++) {
        int col = 16 * j + l15;
        bv[j] = bg[tt * D + col];
        gv[j] = lng[col];
        bb[j] = lnb[col];
    }
#pragma unroll
    for (int i = 0; i < 2; i++)
#pragma unroll
        for (int j = 0; j < 8; j++)
#pragma unroll
            for (int r = 0; r < 4; r++)
                acc[i][j][r] = fmaxf(acc[i][j][r] + bv[j], 0.f);

    float mu[2][4], rs[2][4];
#pragma unroll
    for (int i = 0; i < 2; i++)
#pragma unroll
        for (int r = 0; r < 4; r++) {
            float s = 0.f, s2 = 0.f;
#pragma unroll
            for (int j = 0; j < 8; j++) { float v = acc[i][j][r]; s += v; s2 += v * v; }
#pragma unroll
            for (int m = 1; m < 16; m <<= 1) { s += __shfl_xor(s, m); s2 += __shfl_xor(s2, m); }
            float mm = s * (1.f / 128.f);
            mu[i][r] = mm;
            rs[i][r] = rsqrtf(s2 * (1.f / 128.f) - mm * mm + 1e-5f);
        }

#pragma unroll
    for (int i = 0; i < 2; i++)
#pragma unroll
        for (int r = 0; r < 4; r++) {
            int row = w0 + 16 * i + 4 * lg + r;
#pragma unroll
            for (int j = 0; j < 8; j++) {
                int col = 16 * j + l15;
                float v = (acc[i][j][r] - mu[i][r]) * rs[i][r] * gv[j] + bb[j]
                          + hprev[(size_t)row * D + col];
                hnext[(size_t)row * D + col] = v;
            }
        }
}

// ------------- final FC with un-permute (same MFMA structure, scatter epilogue) -------------
__global__ __launch_bounds__(256) void k_fc(const float* __restrict__ hin,
                                            const float* __restrict__ W,
                                            const float* __restrict__ bias,
                                            const int* __restrict__ inv,
                                            float* __restrict__ out) {
    int wid  = threadIdx.x >> 6;
    int lane = threadIdx.x & 63;
    int w0 = (blockIdx.x * 4 + wid) * 32;
    if (w0 >= NPAD) return;
    int l15 = lane & 15, lg = lane >> 4;

    f32x4 acc[2][8];
#pragma unroll
    for (int i = 0; i < 2; i++)
#pragma unroll
        for (int j = 0; j < 8; j++) acc[i][j] = (f32x4){0.f, 0.f, 0.f, 0.f};

#pragma unroll 1
    for (int ks = 0; ks < 4; ks++) {
        int kb = ks * 32 + 8 * lg;
        float4 rA[2][2], rB[8][2];
#pragma unroll
        for (int i = 0; i < 2; i++) {
            const float* p = hin + (size_t)(w0 + 16 * i + l15) * D + kb;
            rA[i][0] = *(const float4*)p;
            rA[i][1] = *(const float4*)(p + 4);
        }
#pragma unroll
        for (int j = 0; j < 8; j++) {
            const float* p = W + (size_t)(16 * j + l15) * D + kb;
            rB[j][0] = *(const float4*)p;
            rB[j][1] = *(const float4*)(p + 4);
        }
        f16x8 ahi[2], alo[2];
#pragma unroll
        for (int i = 0; i < 2; i++) cvt8(rA[i][0], rA[i][1], ahi[i], alo[i]);
#pragma unroll
        for (int j = 0; j < 8; j++) {
            f16x8 bhi, blo;
            cvt8(rB[j][0], rB[j][1], bhi, blo);
#pragma unroll
            for (int i = 0; i < 2; i++) {
                acc[i][j] = __builtin_amdgcn_mfma_f32_16x16x32_f16(ahi[i], bhi, acc[i][j], 0, 0, 0);
                acc[i][j] = __builtin_amdgcn_mfma_f32_16x16x32_f16(alo[i], bhi, acc[i][j], 0, 0, 0);
                acc[i][j] = __builtin_amdgcn_mfma_f32_16x16x32_f16(ahi[i], blo, acc[i][j], 0, 0, 0);
            }
        }
    }

    float bv[8];
#pragma unroll
    for (int j = 0; j < 8; j++) bv[j] = bias[16 * j + l15];

#pragma unroll
    for (int i = 0; i < 2; i++)
#pragma unroll
        for (int r = 0; r < 4; r++) {
            int row = w0 + 16 * i + 4 * lg + r;
            int orig = inv[row];
            if (orig >= 0) {
#pragma unroll
                for (int j = 0; j < 8; j++)
                    out[(size_t)orig * D + 16 * j + l15] = acc[i][j][r] + bv[j];
            }
        }
}

extern "C" void kernel_launch(void* const* d_in, const int* in_sizes, int n_in,
                              void* d_out, int out_size, void* d_ws, size_t ws_size,
                              hipStream_t stream) {
    const float* x         = (const float*)d_in[0];
    const float* edge_attr = (const float*)d_in[1];
    const float* node_W    = (const float*)d_in[2];
    const float* node_b    = (const float*)d_in[3];
    const float* edge_W    = (const float*)d_in[4];
    const float* edge_b    = (const float*)d_in[5];
    const float* emb       = (const float*)d_in[6];
    const float* ln_g      = (const float*)d_in[7];
    const float* ln_b      = (const float*)d_in[8];
    const float* fc_W      = (const float*)d_in[9];
    const float* fc_b      = (const float*)d_in[10];
    const int*   edge_index = (const int*)d_in[11];
    const int*   node_type  = (const int*)d_in[12];
    const int*   edge_type  = (const int*)d_in[13];
    float* out = (float*)d_out;

    char* w = (char*)d_ws;
    auto alloc = [&](size_t bytes) {
        void* p = (void*)w;
        w += (bytes + 255) & ~(size_t)255;
        return p;
    };
    float*  P     = (float*)alloc((size_t)NPAD * D * 4);   // permuted x / layer buffers
    float*  Q     = (float*)alloc((size_t)NPAD * D * 4);
    float*  G     = (float*)alloc((size_t)NPAD * D * 4);   // aggr
    float4* esort = (float4*)alloc((size_t)EE * 32);
    int*    pos   = (int*)alloc((size_t)NN * 4);
    int*    inv   = (int*)alloc((size_t)NPAD * 4);
    int*    deg   = (int*)alloc((size_t)NN * 4);
    int*    offs  = (int*)alloc((size_t)NN * 4);
    int*    cur   = (int*)alloc((size_t)NN * 4);
    int*    bsum  = (int*)alloc(256 * 4);
    int*    boff  = (int*)alloc(256 * 4);
    int*    pc    = (int*)alloc(256 * 4);
    int*    po    = (int*)alloc(256 * 4);
    int*    meta  = (int*)alloc(8 * 4);

    hipMemsetAsync(deg, 0, (size_t)NN * 4, stream);
    hipMemsetAsync(inv, 0xFF, (size_t)NPAD * 4, stream);   // -1 = "gap row", k_fc skips

    k_pcount<<<NB, 256, 0, stream>>>(node_type, pc);
    k_pscan<<<1, 256, 0, stream>>>(pc, po, meta);
    k_passign<<<NB, 256, 0, stream>>>(node_type, po, meta, pos, inv);
    k_permx<<<(NN * 32 + 255) / 256, 256, 0, stream>>>(x, pos, P);

    k_hist<<<(EE + 255) / 256, 256, 0, stream>>>(edge_index + EE, deg);
    k_scan_bsum<<<NB, 256, 0, stream>>>(deg, bsum);
    k_scan_boff<<<1, 256, 0, stream>>>(bsum, boff);
    k_scan_offs<<<NB, 256, 0, stream>>>(deg, boff, offs, cur);
    k_edge<<<(EE + 255) / 256, 256, 0, stream>>>(edge_attr, edge_W, edge_b, emb,
                                                 edge_index, edge_type, pos, cur, esort);

    // layer rotation: P -> Q -> P -> Q   (in, out per layer)
    const float* hin = P;
    float* outs[LL] = {Q, P, Q};
    for (int l = 0; l < LL; l++) {
        k_gather<<<NN / 2, 256, 0, stream>>>(hin, offs, deg, pos, esort, l, G);
        k_node<<<NBLKM, 256, 0, stream>>>(G, hin,
                                          node_W + (size_t)l * NT * D * D,
                                          node_b + (size_t)l * NT * D,
                                          ln_g + (size_t)l * D,
                                          ln_b + (size_t)l * D,
                                          meta, outs[l]);
        hin = outs[l];
    }
    k_fc<<<NBLKM, 256, 0, stream>>>(hin, fc_W, fc_b, inv, out);
}

// Round 9
// 556.648 us; speedup vs baseline: 1.1192x; 1.0354x over previous
//
#include <hip/hip_runtime.h>
#include <math.h>

#define NN 50000
#define EE 800000
#define D 128
#define EDIM 32
#define LL 3
#define NT 2
#define ET 3
#define NB 196       // ceil(NN/256)
#define NPAD 50080   // >= align64(c0) + c1 for any split; multiple of 32
#define NTILE 1565   // NPAD/32 (32-row wave tiles)
#define NBLKM 392    // ceil(NTILE/4), 4 waves/block

typedef _Float16 f16x8 __attribute__((ext_vector_type(8)));
typedef _Float16 f16x4 __attribute__((ext_vector_type(4)));
typedef float f32x4 __attribute__((ext_vector_type(4)));

// split 8 consecutive fp32 into hi/lo f16 halves (hi + lo == x to ~2^-21 rel)
__device__ __forceinline__ void cvt8(const float4 u, const float4 v, f16x8& hi, f16x8& lo) {
    float x[8] = {u.x, u.y, u.z, u.w, v.x, v.y, v.z, v.w};
#pragma unroll
    for (int e = 0; e < 8; e++) {
        _Float16 h = (_Float16)x[e];
        hi[e] = h;
        lo[e] = (_Float16)(x[e] - (float)h);
    }
}

// ---------------- node-type permutation (deterministic, scan-based) ----------------
// packed counts: low 16 = type0, high 16 = type1 (totals <= 50000 < 65536)
__global__ __launch_bounds__(256) void k_pcount(const int* __restrict__ nt, int* __restrict__ pc) {
    __shared__ int s[256];
    int d = blockIdx.x * 256 + threadIdx.x;
    int ind = 0;
    if (d < NN) ind = (nt[d] == 0) ? 1 : 0x10000;
    s[threadIdx.x] = ind;
    __syncthreads();
    for (int st = 128; st; st >>= 1) {
        if (threadIdx.x < st) s[threadIdx.x] += s[threadIdx.x + st];
        __syncthreads();
    }
    if (threadIdx.x == 0) pc[blockIdx.x] = s[0];
}

__global__ __launch_bounds__(256) void k_pscan(const int* __restrict__ pc, int* __restrict__ po,
                                               int* __restrict__ meta) {
    __shared__ int s[256];
    int t = threadIdx.x;
    int v = (t < NB) ? pc[t] : 0;
    s[t] = v;
    __syncthreads();
    for (int st = 1; st < 256; st <<= 1) {
        int add = (t >= st) ? s[t - st] : 0;
        __syncthreads();
        s[t] += add;
        __syncthreads();
    }
    if (t < NB) po[t] = s[t] - v;                     // exclusive packed block offsets
    if (t == 0) {
        int tot = s[255];
        meta[3] = ((tot & 0xffff) + 63) & ~63;        // aligned base for type-1 region
    }
}

__global__ __launch_bounds__(256) void k_passign(const int* __restrict__ nt, const int* __restrict__ po,
                                                 const int* __restrict__ meta,
                                                 int* __restrict__ pos, int* __restrict__ inv) {
    __shared__ int s[256];
    int t = threadIdx.x;
    int d = blockIdx.x * 256 + t;
    int ty = (d < NN) ? nt[d] : -1;
    int ind = (ty == 0) ? 1 : ((ty == 1) ? 0x10000 : 0);
    s[t] = ind;
    __syncthreads();
    for (int st = 1; st < 256; st <<= 1) {
        int add = (t >= st) ? s[t - st] : 0;
        __syncthreads();
        s[t] += add;
        __syncthreads();
    }
    if (d >= NN) return;
    int excl = s[t] - ind;
    int pop = po[blockIdx.x];
    int p;
    if (ty == 0) p = (pop & 0xffff) + (excl & 0xffff);
    else         p = meta[3] + (pop >> 16) + (excl >> 16);
    pos[d] = p;
    inv[p] = d;
}

// permute x into P (fp32) and P16 (f16 shadow for gather's neighbor reads)
__global__ __launch_bounds__(256) void k_permx(const float* __restrict__ x, const int* __restrict__ pos,
                                               float* __restrict__ h0, _Float16* __restrict__ h0h) {
    int flat = blockIdx.x * 256 + threadIdx.x;
    if (flat >= NN * 32) return;
    int d = flat >> 5, f4 = flat & 31;
    int p = pos[d];
    float4 v = ((const float4*)x)[(size_t)d * 32 + f4];
    ((float4*)h0)[(size_t)p * 32 + f4] = v;
    f16x4 hv;
    hv[0] = (_Float16)v.x; hv[1] = (_Float16)v.y;
    hv[2] = (_Float16)v.z; hv[3] = (_Float16)v.w;
    *(f16x4*)&h0h[(size_t)p * D + 4 * f4] = hv;
}

// ---------------- histogram of dst ----------------
__global__ __launch_bounds__(256) void k_hist(const int* __restrict__ dst, int* __restrict__ deg) {
    int e = blockIdx.x * 256 + threadIdx.x;
    if (e < EE) atomicAdd(&deg[dst[e]], 1);
}

// ---------------- 2-level exclusive scan ----------------
__global__ __launch_bounds__(256) void k_scan_bsum(const int* __restrict__ deg, int* __restrict__ bsum) {
    __shared__ int s[256];
    int t = threadIdx.x;
    int d = blockIdx.x * 256 + t;
    s[t] = (d < NN) ? deg[d] : 0;
    __syncthreads();
    for (int st = 128; st > 0; st >>= 1) {
        if (t < st) s[t] += s[t + st];
        __syncthreads();
    }
    if (t == 0) bsum[blockIdx.x] = s[0];
}

__global__ __launch_bounds__(256) void k_scan_boff(const int* __restrict__ bsum, int* __restrict__ boff) {
    __shared__ int s[256];
    int t = threadIdx.x;
    s[t] = (t < NB) ? bsum[t] : 0;
    __syncthreads();
    for (int st = 1; st < 256; st <<= 1) {
        int add = (t >= st) ? s[t - st] : 0;
        __syncthreads();
        s[t] += add;
        __syncthreads();
    }
    if (t < NB) boff[t] = (t == 0) ? 0 : s[t - 1];
}

__global__ __launch_bounds__(256) void k_scan_offs(const int* __restrict__ deg, const int* __restrict__ boff,
                                                   int* __restrict__ offs, int* __restrict__ cur) {
    __shared__ int s[256];
    int t = threadIdx.x;
    int d = blockIdx.x * 256 + t;
    int v = (d < NN) ? deg[d] : 0;
    s[t] = v;
    __syncthreads();
    for (int st = 1; st < 256; st <<= 1) {
        int add = (t >= st) ? s[t - st] : 0;
        __syncthreads();
        s[t] += add;
        __syncthreads();
    }
    if (d < NN) {
        int excl = s[t] - v + boff[blockIdx.x];
        offs[d] = excl;
        cur[d]  = excl;
    }
}

// ------------- per-edge scalars (all 3 layers) packed + scattered into dst-sorted order -------------
// Weights repacked in LDS as w8[tt][c][8] (6 used: (l,wi) pairs), per-tt stride 264 floats so
// the 3 tt-groups hit distinct banks. Inner loop: 1 ds_read_b128 + 1 ds_read_b64 per c.
// Measured R7/R8: 73.5 -> ~70 us, occupancy 41 -> 52%.
__global__ __launch_bounds__(256) void k_edge(const float* __restrict__ edge_attr,
                                              const float* __restrict__ edge_W,
                                              const float* __restrict__ edge_b,
                                              const float* __restrict__ emb,
                                              const int* __restrict__ ei,
                                              const int* __restrict__ etype,
                                              const int* __restrict__ pos,
                                              int* __restrict__ cur,
                                              float4* __restrict__ esort) {
    __shared__ float w8[3 * 264 + 8];   // [tt][c][8], stride 264 per tt
    __shared__ float ebd[18];           // emb·eW + eb, indexed (l*ET+tt)*2+wi
    int t0 = threadIdx.x;
    for (int i = t0; i < LL * ET * 2 * EDIM; i += 256) {
        int l  = i / 192;          // 192 = ET*2*EDIM
        int r1 = i % 192;
        int tt = r1 / 64;          // 64 = 2*EDIM
        int r2 = r1 % 64;
        int wi = r2 / 32;
        int c  = r2 % 32;
        w8[tt * 264 + c * 8 + l * 2 + wi] = edge_W[i];
    }
    __syncthreads();
    if (t0 < 18) {
        int l = t0 / (ET * 2);
        int rem = t0 % (ET * 2);
        int tt = rem / 2;
        int wi = rem % 2;
        float sum = edge_b[t0];
        const float* em = emb + (l * ET + tt) * EDIM;
        for (int c = 0; c < EDIM; c++) sum += em[c] * w8[tt * 264 + c * 8 + l * 2 + wi];
        ebd[t0] = sum;
    }
    __syncthreads();
    int e = blockIdx.x * 256 + t0;
    if (e >= EE) return;

    float a[EDIM];
    const float4* ap = (const float4*)(edge_attr + (size_t)e * EDIM);
#pragma unroll
    for (int i = 0; i < EDIM / 4; i++) {
        float4 v = ap[i];
        a[4 * i + 0] = v.x; a[4 * i + 1] = v.y; a[4 * i + 2] = v.z; a[4 * i + 3] = v.w;
    }
    int tt = etype[e];
    float dir  = a[EDIM - 2];
    float pump = a[EDIM - 1];
    float sign = dir * 2.f - 1.f;
    float speed = pump * (dir > 0.f ? dir : 1.f);
    int src = ei[e];
    int dst = ei[EE + e];
    int sp = pos[src];
    int p = atomicAdd(&cur[dst], 1);

    float r[6];
#pragma unroll
    for (int l = 0; l < LL; l++) {
        r[2 * l + 0] = ebd[(l * ET + tt) * 2 + 0];
        r[2 * l + 1] = ebd[(l * ET + tt) * 2 + 1];
    }
    const float* wp = w8 + tt * 264;
#pragma unroll
    for (int c = 0; c < EDIM; c++) {
        float4 p0 = *(const float4*)(wp + 8 * c);
        float2 p1 = *(const float2*)(wp + 8 * c + 4);
        float ac = a[c];
        r[0] += ac * p0.x; r[1] += ac * p0.y;
        r[2] += ac * p0.z; r[3] += ac * p0.w;
        r[4] += ac * p1.x; r[5] += ac * p1.y;
    }
    float Av[LL], Bv[LL];
#pragma unroll
    for (int l = 0; l < LL; l++) {
        float r0 = r[2 * l + 0], r1 = r[2 * l + 1];
        float gain = fmaxf(r0, 0.f) + log1pf(expf(-fabsf(r0)));   // stable softplus
        float bias = 0.f;
        if (tt == 1) { gain *= speed; bias = r1 * speed; }        // PUMP == 1
        Av[l] = sign * gain;
        Bv[l] = sign * bias;
    }
    float4 e0 = make_float4(__int_as_float(sp), Av[0], Av[1], Av[2]);
    float4 e1 = make_float4(Bv[0], Bv[1], Bv[2], 0.f);
    esort[(size_t)p * 2 + 0] = e0;
    esort[(size_t)p * 2 + 1] = e1;
}

// ------------- gather: aggr[pos[d]] = sum A*h[spos] - sA*h[pos[d]] + sB -------------
// Neighbor rows read from the f16 shadow (256B/row instead of 512B): gather is
// traffic-bound at ~3 TB/s L2-miss service (R1: 199.5MB / 71.4us), so bytes are the lever.
// Self row (scaled by sA ~ O(16)) stays fp32 for accuracy. 2-deep pipeline (R3's proven depth).
__global__ __launch_bounds__(256) void k_gather(const float* __restrict__ h,
                                                const _Float16* __restrict__ h16,
                                                const int* __restrict__ offs,
                                                const int* __restrict__ deg,
                                                const int* __restrict__ pos,
                                                const float4* __restrict__ esort,
                                                int layer,
                                                float* __restrict__ aggr) {
    __shared__ float4 rbuf[2][32];
    __shared__ float  rsum[2][2];
    int local = threadIdx.x;
    int nb = local >> 7;                    // node within block
    int node = blockIdx.x * 2 + nb;
    int t = local & 127;
    int w = t >> 5;                         // worker 0..3
    int f4 = t & 31;                        // feature-quad lane
    int start = offs[node];
    int n = deg[node];
    int p = pos[node];

    float4 acc = make_float4(0.f, 0.f, 0.f, 0.f);
    float sA = 0.f, sB = 0.f;
    for (int k = w; k < n; k += 8) {
        int k2 = k + 4;
        bool ok2 = (k2 < n);
        size_t i1 = (size_t)(start + k) * 2;
        size_t i2 = ok2 ? (size_t)(start + k2) * 2 : i1;
        float4 e0 = esort[i1];
        float4 e1 = esort[i1 + 1];
        float4 f0 = esort[i2];
        float4 f1 = esort[i2 + 1];
        int s1 = __float_as_int(e0.x);
        int s2 = __float_as_int(f0.x);
        f16x4 h1 = *(const f16x4*)&h16[(size_t)s1 * D + 4 * f4];
        f16x4 h2 = *(const f16x4*)&h16[(size_t)s2 * D + 4 * f4];
        float A1 = (layer == 0) ? e0.y : ((layer == 1) ? e0.z : e0.w);
        float B1 = (layer == 0) ? e1.x : ((layer == 1) ? e1.y : e1.z);
        float A2 = (layer == 0) ? f0.y : ((layer == 1) ? f0.z : f0.w);
        float B2 = (layer == 0) ? f1.x : ((layer == 1) ? f1.y : f1.z);
        if (!ok2) { A2 = 0.f; B2 = 0.f; }
        acc.x += A1 * (float)h1[0] + A2 * (float)h2[0];
        acc.y += A1 * (float)h1[1] + A2 * (float)h2[1];
        acc.z += A1 * (float)h1[2] + A2 * (float)h2[2];
        acc.w += A1 * (float)h1[3] + A2 * (float)h2[3];
        sA += A1 + A2; sB += B1 + B2;
    }
    // combine worker pairs within wave (lanes l and l^32)
    acc.x += __shfl_xor(acc.x, 32); acc.y += __shfl_xor(acc.y, 32);
    acc.z += __shfl_xor(acc.z, 32); acc.w += __shfl_xor(acc.w, 32);
    sA += __shfl_xor(sA, 32); sB += __shfl_xor(sB, 32);
    // cross-wave combine via LDS: upper wave of each node writes, lower reads
    if (((local >> 6) & 1) == 1 && (t & 63) < 32) {
        rbuf[nb][f4] = acc;
        if (f4 == 0) { rsum[nb][0] = sA; rsum[nb][1] = sB; }
    }
    __syncthreads();
    if (((local >> 6) & 1) == 0 && (t & 63) < 32) {
        float4 o = rbuf[nb][f4];
        float sAt = sA + rsum[nb][0];
        float sBt = sB + rsum[nb][1];
        float4 hd = *(const float4*)&h[(size_t)p * D + 4 * f4];   // self row fp32
        float4 r;
        r.x = acc.x + o.x - sAt * hd.x + sBt;
        r.y = acc.y + o.y - sAt * hd.y + sBt;
        r.z = acc.z + o.z - sAt * hd.z + sBt;
        r.w = acc.w + o.w - sAt * hd.w + sBt;
        *(float4*)&aggr[(size_t)p * D + 4 * f4] = r;
    }
}

// ------------- node transform + ReLU + LayerNorm + residual --------------------------
// MFMA split-f16 GEMM: one wave owns a 32x128 output tile; no LDS, no barriers.
// FROZEN at the R3 form (16-row tiles R6 and swapped operands R7 both measured worse).
// Epilogue additionally writes the f16 shadow for the next layer's gather.
__global__ __launch_bounds__(256) void k_node(const float* __restrict__ aggr,
                                              const float* __restrict__ hprev,
                                              const float* __restrict__ Wg,   // node_W + l*NT*D*D
                                              const float* __restrict__ bg,   // node_b + l*NT*D
                                              const float* __restrict__ lng,
                                              const float* __restrict__ lnb,
                                              const int* __restrict__ meta,
                                              float* __restrict__ hnext,
                                              _Float16* __restrict__ hnext16) {
    int wid  = threadIdx.x >> 6;
    int lane = threadIdx.x & 63;
    int w0 = (blockIdx.x * 4 + wid) * 32;          // first row of this wave's tile
    if (w0 >= NPAD) return;
    int l15 = lane & 15, lg = lane >> 4;
    int tt = (w0 >= meta[3]) ? 1 : 0;              // meta[3] is 64-aligned, w0 is 32-aligned
    const float* W = Wg + (size_t)tt * D * D;

    f32x4 acc[2][8];
#pragma unroll
    for (int i = 0; i < 2; i++)
#pragma unroll
        for (int j = 0; j < 8; j++) acc[i][j] = (f32x4){0.f, 0.f, 0.f, 0.f};

#pragma unroll 1
    for (int ks = 0; ks < 4; ks++) {
        int kb = ks * 32 + 8 * lg;                 // float offset within row
        float4 rA[2][2], rB[8][2];
#pragma unroll
        for (int i = 0; i < 2; i++) {
            const float* p = aggr + (size_t)(w0 + 16 * i + l15) * D + kb;
            rA[i][0] = *(const float4*)p;
            rA[i][1] = *(const float4*)(p + 4);
        }
#pragma unroll
        for (int j = 0; j < 8; j++) {
            const float* p = W + (size_t)(16 * j + l15) * D + kb;
            rB[j][0] = *(const float4*)p;
            rB[j][1] = *(const float4*)(p + 4);
        }
        f16x8 ahi[2], alo[2];
#pragma unroll
        for (int i = 0; i < 2; i++) cvt8(rA[i][0], rA[i][1], ahi[i], alo[i]);
#pragma unroll
        for (int j = 0; j < 8; j++) {
            f16x8 bhi, blo;
            cvt8(rB[j][0], rB[j][1], bhi, blo);
#pragma unroll
            for (int i = 0; i < 2; i++) {
                acc[i][j] = __builtin_amdgcn_mfma_f32_16x16x32_f16(ahi[i], bhi, acc[i][j], 0, 0, 0);
                acc[i][j] = __builtin_amdgcn_mfma_f32_16x16x32_f16(alo[i], bhi, acc[i][j], 0, 0, 0);
                acc[i][j] = __builtin_amdgcn_mfma_f32_16x16x32_f16(ahi[i], blo, acc[i][j], 0, 0, 0);
            }
        }
    }

    // epilogue: bias + relu + LN (wave-local: full 128-wide row lives in one 16-lane group) + residual
    float bv[8], gv[8], bb[8];
#pragma unroll
    for (int j = 0; j < 8; j++) {
        int col = 16 * j + l15;
        bv[j] = bg[tt * D + col];
        gv[j] = lng[col];
        bb[j] = lnb[col];
    }
#pragma unroll
    for (int i = 0; i < 2; i++)
#pragma unroll
        for (int j = 0; j < 8; j++)
#pragma unroll
            for (int r = 0; r < 4; r++)
                acc[i][j][r] = fmaxf(acc[i][j][r] + bv[j], 0.f);

    float mu[2][4], rs[2][4];
#pragma unroll
    for (int i = 0; i < 2; i++)
#pragma unroll
        for (int r = 0; r < 4; r++) {
            float s = 0.f, s2 = 0.f;
#pragma unroll
            for (int j = 0; j < 8; j++) { float v = acc[i][j][r]; s += v; s2 += v * v; }
#pragma unroll
            for (int m = 1; m < 16; m <<= 1) { s += __shfl_xor(s, m); s2 += __shfl_xor(s2, m); }
            float mm = s * (1.f / 128.f);
            mu[i][r] = mm;
            rs[i][r] = rsqrtf(s2 * (1.f / 128.f) - mm * mm + 1e-5f);
        }

#pragma unroll
    for (int i = 0; i < 2; i++)
#pragma unroll
        for (int r = 0; r < 4; r++) {
            int row = w0 + 16 * i + 4 * lg + r;
#pragma unroll
            for (int j = 0; j < 8; j++) {
                int col = 16 * j + l15;
                float v = (acc[i][j][r] - mu[i][r]) * rs[i][r] * gv[j] + bb[j]
                          + hprev[(size_t)row * D + col];
                hnext[(size_t)row * D + col] = v;
                hnext16[(size_t)row * D + col] = (_Float16)v;
            }
        }
}

// ------------- final FC with un-permute (same MFMA structure, scatter epilogue) -------------
__global__ __launch_bounds__(256) void k_fc(const float* __restrict__ hin,
                                            const float* __restrict__ W,
                                            const float* __restrict__ bias,
                                            const int* __restrict__ inv,
                                            float* __restrict__ out) {
    int wid  = threadIdx.x >> 6;
    int lane = threadIdx.x & 63;
    int w0 = (blockIdx.x * 4 + wid) * 32;
    if (w0 >= NPAD) return;
    int l15 = lane & 15, lg = lane >> 4;

    f32x4 acc[2][8];
#pragma unroll
    for (int i = 0; i < 2; i++)
#pragma unroll
        for (int j = 0; j < 8; j++) acc[i][j] = (f32x4){0.f, 0.f, 0.f, 0.f};

#pragma unroll 1
    for (int ks = 0; ks < 4; ks++) {
        int kb = ks * 32 + 8 * lg;
        float4 rA[2][2], rB[8][2];
#pragma unroll
        for (int i = 0; i < 2; i++) {
            const float* p = hin + (size_t)(w0 + 16 * i + l15) * D + kb;
            rA[i][0] = *(const float4*)p;
            rA[i][1] = *(const float4*)(p + 4);
        }
#pragma unroll
        for (int j = 0; j < 8; j++) {
            const float* p = W + (size_t)(16 * j + l15) * D + kb;
            rB[j][0] = *(const float4*)p;
            rB[j][1] = *(const float4*)(p + 4);
        }
        f16x8 ahi[2], alo[2];
#pragma unroll
        for (int i = 0; i < 2; i++) cvt8(rA[i][0], rA[i][1], ahi[i], alo[i]);
#pragma unroll
        for (int j = 0; j < 8; j++) {
            f16x8 bhi, blo;
            cvt8(rB[j][0], rB[j][1], bhi, blo);
#pragma unroll
            for (int i = 0; i < 2; i++) {
                acc[i][j] = __builtin_amdgcn_mfma_f32_16x16x32_f16(ahi[i], bhi, acc[i][j], 0, 0, 0);
                acc[i][j] = __builtin_amdgcn_mfma_f32_16x16x32_f16(alo[i], bhi, acc[i][j], 0, 0, 0);
                acc[i][j] = __builtin_amdgcn_mfma_f32_16x16x32_f16(ahi[i], blo, acc[i][j], 0, 0, 0);
            }
        }
    }

    float bv[8];
#pragma unroll
    for (int j = 0; j < 8; j++) bv[j] = bias[16 * j + l15];

#pragma unroll
    for (int i = 0; i < 2; i++)
#pragma unroll
        for (int r = 0; r < 4; r++) {
            int row = w0 + 16 * i + 4 * lg + r;
            int orig = inv[row];
            if (orig >= 0) {
#pragma unroll
                for (int j = 0; j < 8; j++)
                    out[(size_t)orig * D + 16 * j + l15] = acc[i][j][r] + bv[j];
            }
        }
}

extern "C" void kernel_launch(void* const* d_in, const int* in_sizes, int n_in,
                              void* d_out, int out_size, void* d_ws, size_t ws_size,
                              hipStream_t stream) {
    const float* x         = (const float*)d_in[0];
    const float* edge_attr = (const float*)d_in[1];
    const float* node_W    = (const float*)d_in[2];
    const float* node_b    = (const float*)d_in[3];
    const float* edge_W    = (const float*)d_in[4];
    const float* edge_b    = (const float*)d_in[5];
    const float* emb       = (const float*)d_in[6];
    const float* ln_g      = (const float*)d_in[7];
    const float* ln_b      = (const float*)d_in[8];
    const float* fc_W      = (const float*)d_in[9];
    const float* fc_b      = (const float*)d_in[10];
    const int*   edge_index = (const int*)d_in[11];
    const int*   node_type  = (const int*)d_in[12];
    const int*   edge_type  = (const int*)d_in[13];
    float* out = (float*)d_out;

    char* w = (char*)d_ws;
    auto alloc = [&](size_t bytes) {
        void* p = (void*)w;
        w += (bytes + 255) & ~(size_t)255;
        return p;
    };
    float*     P     = (float*)alloc((size_t)NPAD * D * 4);   // permuted x / layer buffers
    float*     Q     = (float*)alloc((size_t)NPAD * D * 4);
    float*     G     = (float*)alloc((size_t)NPAD * D * 4);   // aggr
    _Float16*  P16   = (_Float16*)alloc((size_t)NPAD * D * 2); // f16 shadows for gather
    _Float16*  Q16   = (_Float16*)alloc((size_t)NPAD * D * 2);
    float4*    esort = (float4*)alloc((size_t)EE * 32);
    int*       pos   = (int*)alloc((size_t)NN * 4);
    int*       inv   = (int*)alloc((size_t)NPAD * 4);
    int*       deg   = (int*)alloc((size_t)NN * 4);
    int*       offs  = (int*)alloc((size_t)NN * 4);
    int*       cur   = (int*)alloc((size_t)NN * 4);
    int*       bsum  = (int*)alloc(256 * 4);
    int*       boff  = (int*)alloc(256 * 4);
    int*       pc    = (int*)alloc(256 * 4);
    int*       po    = (int*)alloc(256 * 4);
    int*       meta  = (int*)alloc(8 * 4);

    hipMemsetAsync(deg, 0, (size_t)NN * 4, stream);
    hipMemsetAsync(inv, 0xFF, (size_t)NPAD * 4, stream);   // -1 = "gap row", k_fc skips

    k_pcount<<<NB, 256, 0, stream>>>(node_type, pc);
    k_pscan<<<1, 256, 0, stream>>>(pc, po, meta);
    k_passign<<<NB, 256, 0, stream>>>(node_type, po, meta, pos, inv);
    k_permx<<<(NN * 32 + 255) / 256, 256, 0, stream>>>(x, pos, P, P16);

    k_hist<<<(EE + 255) / 256, 256, 0, stream>>>(edge_index + EE, deg);
    k_scan_bsum<<<NB, 256, 0, stream>>>(deg, bsum);
    k_scan_boff<<<1, 256, 0, stream>>>(bsum, boff);
    k_scan_offs<<<NB, 256, 0, stream>>>(deg, boff, offs, cur);
    k_edge<<<(EE + 255) / 256, 256, 0, stream>>>(edge_attr, edge_W, edge_b, emb,
                                                 edge_index, edge_type, pos, cur, esort);

    // layer rotation: P -> Q -> P -> Q   (in, out per layer); f16 shadows rotate in lockstep
    const float*    hin   = P;
    const _Float16* hin16 = P16;
    float*    outs[LL]   = {Q, P, Q};
    _Float16* outs16[LL] = {Q16, P16, Q16};
    for (int l = 0; l < LL; l++) {
        k_gather<<<NN / 2, 256, 0, stream>>>(hin, hin16, offs, deg, pos, esort, l, G);
        k_node<<<NBLKM, 256, 0, stream>>>(G, hin,
                                          node_W + (size_t)l * NT * D * D,
                                          node_b + (size_t)l * NT * D,
                                          ln_g + (size_t)l * D,
                                          ln_b + (size_t)l * D,
                                          meta, outs[l], outs16[l]);
        hin = outs[l];
        hin16 = outs16[l];
    }
    k_fc<<<NBLKM, 256, 0, stream>>>(hin, fc_W, fc_b, inv, out);
}

// Round 10
// 556.631 us; speedup vs baseline: 1.1192x; 1.0000x over previous
//
#include <hip/hip_runtime.h>
#include <math.h>

#define NN 50000
#define EE 800000
#define D 128
#define EDIM 32
#define LL 3
#define NT 2
#define ET 3
#define NB 196       // ceil(NN/256)
#define NPAD 50080   // >= align64(c0) + c1 for any split; multiple of 32
#define NTILE 1565   // NPAD/32 (32-row wave tiles)
#define NBLKM 392    // ceil(NTILE/4), 4 waves/block
#define WTOT ((LL * NT + 1) * D * D)   // node_W (6 mats) + fc_W (1 mat) = 114688

typedef _Float16 f16x8 __attribute__((ext_vector_type(8)));
typedef _Float16 f16x4 __attribute__((ext_vector_type(4)));
typedef float f32x4 __attribute__((ext_vector_type(4)));

// split 8 consecutive fp32 into hi/lo f16 halves (hi + lo == x to ~2^-21 rel)
__device__ __forceinline__ void cvt8(const float4 u, const float4 v, f16x8& hi, f16x8& lo) {
    float x[8] = {u.x, u.y, u.z, u.w, v.x, v.y, v.z, v.w};
#pragma unroll
    for (int e = 0; e < 8; e++) {
        _Float16 h = (_Float16)x[e];
        hi[e] = h;
        lo[e] = (_Float16)(x[e] - (float)h);
    }
}

// ---------------- one-shot W -> f16 hi/lo split (bit-identical to in-kernel cvt8) ----------------
__global__ __launch_bounds__(256) void k_cvtw(const float* __restrict__ nW, const float* __restrict__ fW,
                                              _Float16* __restrict__ hi, _Float16* __restrict__ lo) {
    int i = blockIdx.x * 256 + threadIdx.x;
    if (i >= WTOT) return;
    float v = (i < LL * NT * D * D) ? nW[i] : fW[i - LL * NT * D * D];
    _Float16 h = (_Float16)v;
    hi[i] = h;
    lo[i] = (_Float16)(v - (float)h);
}

// ---------------- node-type permutation (deterministic, scan-based) ----------------
// packed counts: low 16 = type0, high 16 = type1 (totals <= 50000 < 65536)
__global__ __launch_bounds__(256) void k_pcount(const int* __restrict__ nt, int* __restrict__ pc) {
    __shared__ int s[256];
    int d = blockIdx.x * 256 + threadIdx.x;
    int ind = 0;
    if (d < NN) ind = (nt[d] == 0) ? 1 : 0x10000;
    s[threadIdx.x] = ind;
    __syncthreads();
    for (int st = 128; st; st >>= 1) {
        if (threadIdx.x < st) s[threadIdx.x] += s[threadIdx.x + st];
        __syncthreads();
    }
    if (threadIdx.x == 0) pc[blockIdx.x] = s[0];
}

__global__ __launch_bounds__(256) void k_pscan(const int* __restrict__ pc, int* __restrict__ po,
                                               int* __restrict__ meta) {
    __shared__ int s[256];
    int t = threadIdx.x;
    int v = (t < NB) ? pc[t] : 0;
    s[t] = v;
    __syncthreads();
    for (int st = 1; st < 256; st <<= 1) {
        int add = (t >= st) ? s[t - st] : 0;
        __syncthreads();
        s[t] += add;
        __syncthreads();
    }
    if (t < NB) po[t] = s[t] - v;                     // exclusive packed block offsets
    if (t == 0) {
        int tot = s[255];
        meta[3] = ((tot & 0xffff) + 63) & ~63;        // aligned base for type-1 region
    }
}

__global__ __launch_bounds__(256) void k_passign(const int* __restrict__ nt, const int* __restrict__ po,
                                                 const int* __restrict__ meta,
                                                 int* __restrict__ pos, int* __restrict__ inv) {
    __shared__ int s[256];
    int t = threadIdx.x;
    int d = blockIdx.x * 256 + t;
    int ty = (d < NN) ? nt[d] : -1;
    int ind = (ty == 0) ? 1 : ((ty == 1) ? 0x10000 : 0);
    s[t] = ind;
    __syncthreads();
    for (int st = 1; st < 256; st <<= 1) {
        int add = (t >= st) ? s[t - st] : 0;
        __syncthreads();
        s[t] += add;
        __syncthreads();
    }
    if (d >= NN) return;
    int excl = s[t] - ind;
    int pop = po[blockIdx.x];
    int p;
    if (ty == 0) p = (pop & 0xffff) + (excl & 0xffff);
    else         p = meta[3] + (pop >> 16) + (excl >> 16);
    pos[d] = p;
    inv[p] = d;
}

// permute x into P (fp32) and P16 (f16 shadow for gather's neighbor reads)
__global__ __launch_bounds__(256) void k_permx(const float* __restrict__ x, const int* __restrict__ pos,
                                               float* __restrict__ h0, _Float16* __restrict__ h0h) {
    int flat = blockIdx.x * 256 + threadIdx.x;
    if (flat >= NN * 32) return;
    int d = flat >> 5, f4 = flat & 31;
    int p = pos[d];
    float4 v = ((const float4*)x)[(size_t)d * 32 + f4];
    ((float4*)h0)[(size_t)p * 32 + f4] = v;
    f16x4 hv;
    hv[0] = (_Float16)v.x; hv[1] = (_Float16)v.y;
    hv[2] = (_Float16)v.z; hv[3] = (_Float16)v.w;
    *(f16x4*)&h0h[(size_t)p * D + 4 * f4] = hv;
}

// ---------------- histogram of dst ----------------
__global__ __launch_bounds__(256) void k_hist(const int* __restrict__ dst, int* __restrict__ deg) {
    int e = blockIdx.x * 256 + threadIdx.x;
    if (e < EE) atomicAdd(&deg[dst[e]], 1);
}

// ---------------- 2-level exclusive scan ----------------
__global__ __launch_bounds__(256) void k_scan_bsum(const int* __restrict__ deg, int* __restrict__ bsum) {
    __shared__ int s[256];
    int t = threadIdx.x;
    int d = blockIdx.x * 256 + t;
    s[t] = (d < NN) ? deg[d] : 0;
    __syncthreads();
    for (int st = 128; st > 0; st >>= 1) {
        if (t < st) s[t] += s[t + st];
        __syncthreads();
    }
    if (t == 0) bsum[blockIdx.x] = s[0];
}

__global__ __launch_bounds__(256) void k_scan_boff(const int* __restrict__ bsum, int* __restrict__ boff) {
    __shared__ int s[256];
    int t = threadIdx.x;
    s[t] = (t < NB) ? bsum[t] : 0;
    __syncthreads();
    for (int st = 1; st < 256; st <<= 1) {
        int add = (t >= st) ? s[t - st] : 0;
        __syncthreads();
        s[t] += add;
        __syncthreads();
    }
    if (t < NB) boff[t] = (t == 0) ? 0 : s[t - 1];
}

__global__ __launch_bounds__(256) void k_scan_offs(const int* __restrict__ deg, const int* __restrict__ boff,
                                                   int* __restrict__ offs, int* __restrict__ cur) {
    __shared__ int s[256];
    int t = threadIdx.x;
    int d = blockIdx.x * 256 + t;
    int v = (d < NN) ? deg[d] : 0;
    s[t] = v;
    __syncthreads();
    for (int st = 1; st < 256; st <<= 1) {
        int add = (t >= st) ? s[t - st] : 0;
        __syncthreads();
        s[t] += add;
        __syncthreads();
    }
    if (d < NN) {
        int excl = s[t] - v + boff[blockIdx.x];
        offs[d] = excl;
        cur[d]  = excl;
    }
}

// ------------- per-edge scalars (all 3 layers) packed + scattered into dst-sorted order -------------
// Weights repacked in LDS as w8[tt][c][8] (6 used: (l,wi) pairs), per-tt stride 264 floats so
// the 3 tt-groups hit distinct banks. Inner loop: 1 ds_read_b128 + 1 ds_read_b64 per c.
// Measured R7/R8: 73.5 -> ~70 us, occupancy 41 -> 52%.
__global__ __launch_bounds__(256) void k_edge(const float* __restrict__ edge_attr,
                                              const float* __restrict__ edge_W,
                                              const float* __restrict__ edge_b,
                                              const float* __restrict__ emb,
                                              const int* __restrict__ ei,
                                              const int* __restrict__ etype,
                                              const int* __restrict__ pos,
                                              int* __restrict__ cur,
                                              float4* __restrict__ esort) {
    __shared__ float w8[3 * 264 + 8];   // [tt][c][8], stride 264 per tt
    __shared__ float ebd[18];           // emb·eW + eb, indexed (l*ET+tt)*2+wi
    int t0 = threadIdx.x;
    for (int i = t0; i < LL * ET * 2 * EDIM; i += 256) {
        int l  = i / 192;          // 192 = ET*2*EDIM
        int r1 = i % 192;
        int tt = r1 / 64;          // 64 = 2*EDIM
        int r2 = r1 % 64;
        int wi = r2 / 32;
        int c  = r2 % 32;
        w8[tt * 264 + c * 8 + l * 2 + wi] = edge_W[i];
    }
    __syncthreads();
    if (t0 < 18) {
        int l = t0 / (ET * 2);
        int rem = t0 % (ET * 2);
        int tt = rem / 2;
        int wi = rem % 2;
        float sum = edge_b[t0];
        const float* em = emb + (l * ET + tt) * EDIM;
        for (int c = 0; c < EDIM; c++) sum += em[c] * w8[tt * 264 + c * 8 + l * 2 + wi];
        ebd[t0] = sum;
    }
    __syncthreads();
    int e = blockIdx.x * 256 + t0;
    if (e >= EE) return;

    float a[EDIM];
    const float4* ap = (const float4*)(edge_attr + (size_t)e * EDIM);
#pragma unroll
    for (int i = 0; i < EDIM / 4; i++) {
        float4 v = ap[i];
        a[4 * i + 0] = v.x; a[4 * i + 1] = v.y; a[4 * i + 2] = v.z; a[4 * i + 3] = v.w;
    }
    int tt = etype[e];
    float dir  = a[EDIM - 2];
    float pump = a[EDIM - 1];
    float sign = dir * 2.f - 1.f;
    float speed = pump * (dir > 0.f ? dir : 1.f);
    int src = ei[e];
    int dst = ei[EE + e];
    int sp = pos[src];
    int p = atomicAdd(&cur[dst], 1);

    float r[6];
#pragma unroll
    for (int l = 0; l < LL; l++) {
        r[2 * l + 0] = ebd[(l * ET + tt) * 2 + 0];
        r[2 * l + 1] = ebd[(l * ET + tt) * 2 + 1];
    }
    const float* wp = w8 + tt * 264;
#pragma unroll
    for (int c = 0; c < EDIM; c++) {
        float4 p0 = *(const float4*)(wp + 8 * c);
        float2 p1 = *(const float2*)(wp + 8 * c + 4);
        float ac = a[c];
        r[0] += ac * p0.x; r[1] += ac * p0.y;
        r[2] += ac * p0.z; r[3] += ac * p0.w;
        r[4] += ac * p1.x; r[5] += ac * p1.y;
    }
    float Av[LL], Bv[LL];
#pragma unroll
    for (int l = 0; l < LL; l++) {
        float r0 = r[2 * l + 0], r1 = r[2 * l + 1];
        float gain = fmaxf(r0, 0.f) + log1pf(expf(-fabsf(r0)));   // stable softplus
        float bias = 0.f;
        if (tt == 1) { gain *= speed; bias = r1 * speed; }        // PUMP == 1
        Av[l] = sign * gain;
        Bv[l] = sign * bias;
    }
    float4 e0 = make_float4(__int_as_float(sp), Av[0], Av[1], Av[2]);
    float4 e1 = make_float4(Bv[0], Bv[1], Bv[2], 0.f);
    esort[(size_t)p * 2 + 0] = e0;
    esort[(size_t)p * 2 + 1] = e1;
}

// ------------- gather: aggr[pos[d]] = sum A*h[spos] - sA*h[pos[d]] + sB -------------
// Neighbor rows read from the f16 shadow (256B/row instead of 512B): gather is
// traffic-bound at ~3 TB/s L2-miss service. Self row (scaled by sA ~ O(16)) stays fp32.
// 2-deep pipeline (R3's proven depth). Measured R9: -4 us/dispatch.
__global__ __launch_bounds__(256) void k_gather(const float* __restrict__ h,
                                                const _Float16* __restrict__ h16,
                                                const int* __restrict__ offs,
                                                const int* __restrict__ deg,
                                                const int* __restrict__ pos,
                                                const float4* __restrict__ esort,
                                                int layer,
                                                float* __restrict__ aggr) {
    __shared__ float4 rbuf[2][32];
    __shared__ float  rsum[2][2];
    int local = threadIdx.x;
    int nb = local >> 7;                    // node within block
    int node = blockIdx.x * 2 + nb;
    int t = local & 127;
    int w = t >> 5;                         // worker 0..3
    int f4 = t & 31;                        // feature-quad lane
    int start = offs[node];
    int n = deg[node];
    int p = pos[node];

    float4 acc = make_float4(0.f, 0.f, 0.f, 0.f);
    float sA = 0.f, sB = 0.f;
    for (int k = w; k < n; k += 8) {
        int k2 = k + 4;
        bool ok2 = (k2 < n);
        size_t i1 = (size_t)(start + k) * 2;
        size_t i2 = ok2 ? (size_t)(start + k2) * 2 : i1;
        float4 e0 = esort[i1];
        float4 e1 = esort[i1 + 1];
        float4 f0 = esort[i2];
        float4 f1 = esort[i2 + 1];
        int s1 = __float_as_int(e0.x);
        int s2 = __float_as_int(f0.x);
        f16x4 h1 = *(const f16x4*)&h16[(size_t)s1 * D + 4 * f4];
        f16x4 h2 = *(const f16x4*)&h16[(size_t)s2 * D + 4 * f4];
        float A1 = (layer == 0) ? e0.y : ((layer == 1) ? e0.z : e0.w);
        float B1 = (layer == 0) ? e1.x : ((layer == 1) ? e1.y : e1.z);
        float A2 = (layer == 0) ? f0.y : ((layer == 1) ? f0.z : f0.w);
        float B2 = (layer == 0) ? f1.x : ((layer == 1) ? f1.y : f1.z);
        if (!ok2) { A2 = 0.f; B2 = 0.f; }
        acc.x += A1 * (float)h1[0] + A2 * (float)h2[0];
        acc.y += A1 * (float)h1[1] + A2 * (float)h2[1];
        acc.z += A1 * (float)h1[2] + A2 * (float)h2[2];
        acc.w += A1 * (float)h1[3] + A2 * (float)h2[3];
        sA += A1 + A2; sB += B1 + B2;
    }
    // combine worker pairs within wave (lanes l and l^32)
    acc.x += __shfl_xor(acc.x, 32); acc.y += __shfl_xor(acc.y, 32);
    acc.z += __shfl_xor(acc.z, 32); acc.w += __shfl_xor(acc.w, 32);
    sA += __shfl_xor(sA, 32); sB += __shfl_xor(sB, 32);
    // cross-wave combine via LDS: upper wave of each node writes, lower reads
    if (((local >> 6) & 1) == 1 && (t & 63) < 32) {
        rbuf[nb][f4] = acc;
        if (f4 == 0) { rsum[nb][0] = sA; rsum[nb][1] = sB; }
    }
    __syncthreads();
    if (((local >> 6) & 1) == 0 && (t & 63) < 32) {
        float4 o = rbuf[nb][f4];
        float sAt = sA + rsum[nb][0];
        float sBt = sB + rsum[nb][1];
        float4 hd = *(const float4*)&h[(size_t)p * D + 4 * f4];   // self row fp32
        float4 r;
        r.x = acc.x + o.x - sAt * hd.x + sBt;
        r.y = acc.y + o.y - sAt * hd.y + sBt;
        r.z = acc.z + o.z - sAt * hd.z + sBt;
        r.w = acc.w + o.w - sAt * hd.w + sBt;
        *(float4*)&aggr[(size_t)p * D + 4 * f4] = r;
    }
}

// ------------- node transform + ReLU + LayerNorm + residual --------------------------
// MFMA split-f16 GEMM: one wave owns a 32x128 output tile; no LDS, no barriers.
// FROZEN structure (R6 16-row and R7 swap both measured worse). B-side (W) now loads
// PRECOMPUTED f16 hi/lo directly: halves per-wave W bytes (64->32KB) and removes the
// per-ks cvt8 chain for W. Math bit-identical to the in-kernel split.
__global__ __launch_bounds__(256) void k_node(const float* __restrict__ aggr,
                                              const float* __restrict__ hprev,
                                              const _Float16* __restrict__ Whi,  // + l*NT*D*D
                                              const _Float16* __restrict__ Wlo,
                                              const float* __restrict__ bg,      // node_b + l*NT*D
                                              const float* __restrict__ lng,
                                              const float* __restrict__ lnb,
                                              const int* __restrict__ meta,
                                              float* __restrict__ hnext,
                                              _Float16* __restrict__ hnext16) {
    int wid  = threadIdx.x >> 6;
    int lane = threadIdx.x & 63;
    int w0 = (blockIdx.x * 4 + wid) * 32;          // first row of this wave's tile
    if (w0 >= NPAD) return;
    int l15 = lane & 15, lg = lane >> 4;
    int tt = (w0 >= meta[3]) ? 1 : 0;              // meta[3] is 64-aligned, w0 is 32-aligned
    const _Float16* Wh = Whi + (size_t)tt * D * D;
    const _Float16* Wl = Wlo + (size_t)tt * D * D;

    f32x4 acc[2][8];
#pragma unroll
    for (int i = 0; i < 2; i++)
#pragma unroll
        for (int j = 0; j < 8; j++) acc[i][j] = (f32x4){0.f, 0.f, 0.f, 0.f};

#pragma unroll 1
    for (int ks = 0; ks < 4; ks++) {
        int kb = ks * 32 + 8 * lg;                 // element offset within row
        float4 rA[2][2];
        f16x8 bhi[8], blo[8];
#pragma unroll
        for (int i = 0; i < 2; i++) {
            const float* p = aggr + (size_t)(w0 + 16 * i + l15) * D + kb;
            rA[i][0] = *(const float4*)p;
            rA[i][1] = *(const float4*)(p + 4);
        }
#pragma unroll
        for (int j = 0; j < 8; j++) {
            size_t off = (size_t)(16 * j + l15) * D + kb;
            bhi[j] = *(const f16x8*)&Wh[off];
            blo[j] = *(const f16x8*)&Wl[off];
        }
        f16x8 ahi[2], alo[2];
#pragma unroll
        for (int i = 0; i < 2; i++) cvt8(rA[i][0], rA[i][1], ahi[i], alo[i]);
#pragma unroll
        for (int j = 0; j < 8; j++) {
#pragma unroll
            for (int i = 0; i < 2; i++) {
                acc[i][j] = __builtin_amdgcn_mfma_f32_16x16x32_f16(ahi[i], bhi[j], acc[i][j], 0, 0, 0);
                acc[i][j] = __builtin_amdgcn_mfma_f32_16x16x32_f16(alo[i], bhi[j], acc[i][j], 0, 0, 0);
                acc[i][j] = __builtin_amdgcn_mfma_f32_16x16x32_f16(ahi[i], blo[j], acc[i][j], 0, 0, 0);
            }
        }
    }

    // epilogue: bias + relu + LN (wave-local: full 128-wide row lives in one 16-lane group) + residual
    float bv[8], gv[8], bb[8];
#pragma unroll
    for (int j = 0; j < 8; j++) {
        int col = 16 * j + l15;
        bv[j] = bg[tt * D + col];
        gv[j] = lng[col];
        bb[j] = lnb[col];
    }
#pragma unroll
    for (int i = 0; i < 2; i++)
#pragma unroll
        for (int j = 0; j < 8; j++)
#pragma unroll
            for (int r = 0; r < 4; r++)
                acc[i][j][r] = fmaxf(acc[i][j][r] + bv[j], 0.f);

    float mu[2][4], rs[2][4];
#pragma unroll
    for (int i = 0; i < 2; i++)
#pragma unroll
        for (int r = 0; r < 4; r++) {
            float s = 0.f, s2 = 0.f;
#pragma unroll
            for (int j = 0; j < 8; j++) { float v = acc[i][j][r]; s += v; s2 += v * v; }
#pragma unroll
            for (int m = 1; m < 16; m <<= 1) { s += __shfl_xor(s, m); s2 += __shfl_xor(s2, m); }
            float mm = s * (1.f / 128.f);
            mu[i][r] = mm;
            rs[i][r] = rsqrtf(s2 * (1.f / 128.f) - mm * mm + 1e-5f);
        }

#pragma unroll
    for (int i = 0; i < 2; i++)
#pragma unroll
        for (int r = 0; r < 4; r++) {
            int row = w0 + 16 * i + 4 * lg + r;
#pragma unroll
            for (int j = 0; j < 8; j++) {
                int col = 16 * j + l15;
                float v = (acc[i][j][r] - mu[i][r]) * rs[i][r] * gv[j] + bb[j]
                          + hprev[(size_t)row * D + col];
                hnext[(size_t)row * D + col] = v;
                hnext16[(size_t)row * D + col] = (_Float16)v;
            }
        }
}

// ------------- final FC with un-permute (same MFMA structure, scatter epilogue) -------------
__global__ __launch_bounds__(256) void k_fc(const float* __restrict__ hin,
                                            const _Float16* __restrict__ Whi,   // + LL*NT*D*D
                                            const _Float16* __restrict__ Wlo,
                                            const float* __restrict__ bias,
                                            const int* __restrict__ inv,
                                            float* __restrict__ out) {
    int wid  = threadIdx.x >> 6;
    int lane = threadIdx.x & 63;
    int w0 = (blockIdx.x * 4 + wid) * 32;
    if (w0 >= NPAD) return;
    int l15 = lane & 15, lg = lane >> 4;

    f32x4 acc[2][8];
#pragma unroll
    for (int i = 0; i < 2; i++)
#pragma unroll
        for (int j = 0; j < 8; j++) acc[i][j] = (f32x4){0.f, 0.f, 0.f, 0.f};

#pragma unroll 1
    for (int ks = 0; ks < 4; ks++) {
        int kb = ks * 32 + 8 * lg;
        float4 rA[2][2];
        f16x8 bhi[8], blo[8];
#pragma unroll
        for (int i = 0; i < 2; i++) {
            const float* p = hin + (size_t)(w0 + 16 * i + l15) * D + kb;
            rA[i][0] = *(const float4*)p;
            rA[i][1] = *(const float4*)(p + 4);
        }
#pragma unroll
        for (int j = 0; j < 8; j++) {
            size_t off = (size_t)(16 * j + l15) * D + kb;
            bhi[j] = *(const f16x8*)&Whi[off];
            blo[j] = *(const f16x8*)&Wlo[off];
        }
        f16x8 ahi[2], alo[2];
#pragma unroll
        for (int i = 0; i < 2; i++) cvt8(rA[i][0], rA[i][1], ahi[i], alo[i]);
#pragma unroll
        for (int j = 0; j < 8; j++) {
#pragma unroll
            for (int i = 0; i < 2; i++) {
                acc[i][j] = __builtin_amdgcn_mfma_f32_16x16x32_f16(ahi[i], bhi[j], acc[i][j], 0, 0, 0);
                acc[i][j] = __builtin_amdgcn_mfma_f32_16x16x32_f16(alo[i], bhi[j], acc[i][j], 0, 0, 0);
                acc[i][j] = __builtin_amdgcn_mfma_f32_16x16x32_f16(ahi[i], blo[j], acc[i][j], 0, 0, 0);
            }
        }
    }

    float bv[8];
#pragma unroll
    for (int j = 0; j < 8; j++) bv[j] = bias[16 * j + l15];

#pragma unroll
    for (int i = 0; i < 2; i++)
#pragma unroll
        for (int r = 0; r < 4; r++) {
            int row = w0 + 16 * i + 4 * lg + r;
            int orig = inv[row];
            if (orig >= 0) {
#pragma unroll
                for (int j = 0; j < 8; j++)
                    out[(size_t)orig * D + 16 * j + l15] = acc[i][j][r] + bv[j];
            }
        }
}

extern "C" void kernel_launch(void* const* d_in, const int* in_sizes, int n_in,
                              void* d_out, int out_size, void* d_ws, size_t ws_size,
                              hipStream_t stream) {
    const float* x         = (const float*)d_in[0];
    const float* edge_attr = (const float*)d_in[1];
    const float* node_W    = (const float*)d_in[2];
    const float* node_b    = (const float*)d_in[3];
    const float* edge_W    = (const float*)d_in[4];
    const float* edge_b    = (const float*)d_in[5];
    const float* emb       = (const float*)d_in[6];
    const float* ln_g      = (const float*)d_in[7];
    const float* ln_b      = (const float*)d_in[8];
    const float* fc_W      = (const float*)d_in[9];
    const float* fc_b      = (const float*)d_in[10];
    const int*   edge_index = (const int*)d_in[11];
    const int*   node_type  = (const int*)d_in[12];
    const int*   edge_type  = (const int*)d_in[13];
    float* out = (float*)d_out;

    char* w = (char*)d_ws;
    auto alloc = [&](size_t bytes) {
        void* p = (void*)w;
        w += (bytes + 255) & ~(size_t)255;
        return p;
    };
    float*     P     = (float*)alloc((size_t)NPAD * D * 4);   // permuted x / layer buffers
    float*     Q     = (float*)alloc((size_t)NPAD * D * 4);
    float*     G     = (float*)alloc((size_t)NPAD * D * 4);   // aggr
    _Float16*  P16   = (_Float16*)alloc((size_t)NPAD * D * 2); // f16 shadows for gather
    _Float16*  Q16   = (_Float16*)alloc((size_t)NPAD * D * 2);
    _Float16*  Whi   = (_Float16*)alloc((size_t)WTOT * 2);     // precomputed W hi/lo
    _Float16*  Wlo   = (_Float16*)alloc((size_t)WTOT * 2);
    float4*    esort = (float4*)alloc((size_t)EE * 32);
    int*       pos   = (int*)alloc((size_t)NN * 4);
    int*       inv   = (int*)alloc((size_t)NPAD * 4);
    int*       deg   = (int*)alloc((size_t)NN * 4);
    int*       offs  = (int*)alloc((size_t)NN * 4);
    int*       cur   = (int*)alloc((size_t)NN * 4);
    int*       bsum  = (int*)alloc(256 * 4);
    int*       boff  = (int*)alloc(256 * 4);
    int*       pc    = (int*)alloc(256 * 4);
    int*       po    = (int*)alloc(256 * 4);
    int*       meta  = (int*)alloc(8 * 4);

    hipMemsetAsync(deg, 0, (size_t)NN * 4, stream);
    hipMemsetAsync(inv, 0xFF, (size_t)NPAD * 4, stream);   // -1 = "gap row", k_fc skips

    k_cvtw<<<(WTOT + 255) / 256, 256, 0, stream>>>(node_W, fc_W, Whi, Wlo);
    k_pcount<<<NB, 256, 0, stream>>>(node_type, pc);
    k_pscan<<<1, 256, 0, stream>>>(pc, po, meta);
    k_passign<<<NB, 256, 0, stream>>>(node_type, po, meta, pos, inv);
    k_permx<<<(NN * 32 + 255) / 256, 256, 0, stream>>>(x, pos, P, P16);

    k_hist<<<(EE + 255) / 256, 256, 0, stream>>>(edge_index + EE, deg);
    k_scan_bsum<<<NB, 256, 0, stream>>>(deg, bsum);
    k_scan_boff<<<1, 256, 0, stream>>>(bsum, boff);
    k_scan_offs<<<NB, 256, 0, stream>>>(deg, boff, offs, cur);
    k_edge<<<(EE + 255) / 256, 256, 0, stream>>>(edge_attr, edge_W, edge_b, emb,
                                                 edge_index, edge_type, pos, cur, esort);

    // layer rotation: P -> Q -> P -> Q   (in, out per layer); f16 shadows rotate in lockstep
    const float*    hin   = P;
    const _Float16* hin16 = P16;
    float*    outs[LL]   = {Q, P, Q};
    _Float16* outs16[LL] = {Q16, P16, Q16};
    for (int l = 0; l < LL; l++) {
        k_gather<<<NN / 2, 256, 0, stream>>>(hin, hin16, offs, deg, pos, esort, l, G);
        k_node<<<NBLKM, 256, 0, stream>>>(G, hin,
                                          Whi + (size_t)l * NT * D * D,
                                          Wlo + (size_t)l * NT * D * D,
                                          node_b + (size_t)l * NT * D,
                                          ln_g + (size_t)l * D,
                                          ln_b + (size_t)l * D,
                                          meta, outs[l], outs16[l]);
        hin = outs[l];
        hin16 = outs16[l];
    }
    k_fc<<<NBLKM, 256, 0, stream>>>(hin, Whi + (size_t)LL * NT * D * D,
                                    Wlo + (size_t)LL * NT * D * D, fc_b, inv, out);
}